// Round 1
// baseline (1324.331 us; speedup 1.0000x reference)
//
#include <hip/hip_runtime.h>
#include <math.h>

#define T_STEPS 4
#define NNODES 50000
#define NEDGES 400000
#define FIN 128   // input feature dim for both layers
#define NBINS 8192
#define BINSHIFT 19  // 32-13
#define EQCAP 4096
#define DSHARD 6250  // NNODES/8 (src shard width)

__device__ __forceinline__ float sigmoidf_(float x) { return 1.0f / (1.0f + __expf(-x)); }

__device__ __forceinline__ unsigned int key_of(float s) {
    unsigned int u = __float_as_uint(s);
    return (u & 0x80000000u) ? ~u : (u | 0x80000000u);
}

__device__ __forceinline__ unsigned short f2bf(float f) {
    unsigned int u = __float_as_uint(f);
    unsigned int r = (u + 0x7FFFu + ((u >> 16) & 1u)) >> 16;
    return (unsigned short)r;
}
__device__ __forceinline__ float bf2f(unsigned short h) {
    return __uint_as_float(((unsigned int)h) << 16);
}

// ---------------- norms of the two scorers ----------------
__global__ void norm_kernel(const float* __restrict__ s0, const float* __restrict__ s1,
                            float* __restrict__ norms) {
    __shared__ float red[128];
    int tid = threadIdx.x;  // 128 threads
    float a = s0[tid];
    red[tid] = a * a;
    __syncthreads();
    for (int off = 64; off > 0; off >>= 1) { if (tid < off) red[tid] += red[tid + off]; __syncthreads(); }
    if (tid == 0) norms[0] = sqrtf(red[0]);
    __syncthreads();
    float b = s1[tid];
    red[tid] = b * b;
    __syncthreads();
    for (int off = 64; off > 0; off >>= 1) { if (tid < off) red[tid] += red[tid + off]; __syncthreads(); }
    if (tid == 0) norms[1] = sqrtf(red[0]);
}

// ---------------- L0 scores for ALL t + topk histogram ----------------
// grid: (ceil(N/256), T_STEPS)
__global__ void scores_hist4_kernel(const float* __restrict__ node_embs, const float* __restrict__ scorer,
                                    const float* __restrict__ norms,
                                    const float* __restrict__ mask, float* __restrict__ scores4,
                                    int* __restrict__ ghist4, int N) {
    __shared__ float sc[FIN];
    if (threadIdx.x < FIN) sc[threadIdx.x] = scorer[threadIdx.x];
    __syncthreads();
    int t = blockIdx.y;
    int n = blockIdx.x * blockDim.x + threadIdx.x;
    if (n >= N) return;
    const float4* xr = (const float4*)(node_embs + ((size_t)t * N + n) * FIN);
    float acc = 0.f;
#pragma unroll 8
    for (int k4 = 0; k4 < FIN / 4; k4++) {
        float4 v = xr[k4];
        acc += v.x * sc[k4 * 4] + v.y * sc[k4 * 4 + 1] + v.z * sc[k4 * 4 + 2] + v.w * sc[k4 * 4 + 3];
    }
    float s = acc / norms[0] + mask[(size_t)t * N + n];
    scores4[(size_t)t * N + n] = s;
    atomicAdd(&ghist4[t * NBINS + (key_of(s) >> BINSHIFT)], 1);
}

// ---------------- parallel top-k collect: each block re-derives critical bin ----------------
// grid: (196, ntasks). task strides: scores N, ghist NBINS, cnts 2, gt 128, eq EQCAP
__global__ void __launch_bounds__(256)
topk_collect_kernel(const float* __restrict__ scores_b, const int* __restrict__ ghist_b,
                    int* __restrict__ cnts_b, int* __restrict__ gt_idx_b, float* __restrict__ gt_val_b,
                    int* __restrict__ eq_idx_b, float* __restrict__ eq_val_b, int N, int K) {
    __shared__ int h[NBINS];
    __shared__ int part[256];
    __shared__ int s_bin;
    int tid = threadIdx.x;
    int task = blockIdx.y;
    const int* gh = ghist_b + (size_t)task * NBINS;
    for (int i = tid; i < NBINS; i += 256) h[i] = gh[i];
    __syncthreads();
    int s = 0;
#pragma unroll
    for (int i = 0; i < NBINS / 256; i++) s += h[tid * (NBINS / 256) + i];
    part[tid] = s;
    __syncthreads();
    for (int off = 1; off < 256; off <<= 1) {
        int v = (tid + off < 256) ? part[tid + off] : 0;
        __syncthreads();
        part[tid] += v;
        __syncthreads();
    }
    {
        int run = (tid == 255) ? 0 : part[tid + 1];
        const int CH = NBINS / 256;
        for (int b = tid * CH + CH - 1; b >= tid * CH; b--) {
            int Sb = run + h[b];
            if (Sb >= K && run < K) s_bin = b;
            run = Sb;
        }
    }
    __syncthreads();
    int bin = s_bin;
    const float* scores = scores_b + (size_t)task * N;
    int* cg = cnts_b + task * 2;
    for (int n = blockIdx.x * 256 + tid; n < N; n += gridDim.x * 256) {
        float sc = scores[n];
        unsigned int key = key_of(sc);
        int kb = (int)(key >> BINSHIFT);
        if (kb > bin) {
            int p = atomicAdd(&cg[0], 1);
            gt_idx_b[task * 128 + p] = n; gt_val_b[task * 128 + p] = sc;
        } else if (kb == bin) {
            int p = atomicAdd(&cg[1], 1);
            if (p < EQCAP) { eq_idx_b[task * EQCAP + p] = n; eq_val_b[task * EQCAP + p] = sc; }
        }
    }
}

// ---------------- finish: exact rank + sort + z build; self-zero ghist & cnts ----------------
// grid: (ntasks). need = K - cnt_gt. z[r*K+j] = X[idx_j*FIN+r]*tanh(val_j)
template <int K>
__global__ void __launch_bounds__(1024)
topk_finish_kernel(int* __restrict__ ghist_b, int* __restrict__ cnts_b,
                   const int* __restrict__ gt_idx_b, const float* __restrict__ gt_val_b,
                   const int* __restrict__ eq_idx_b, const float* __restrict__ eq_val_b,
                   const float* __restrict__ X_b, float* __restrict__ z_b, int N) {
    __shared__ int sidx[K];
    __shared__ float sval[K];
    __shared__ unsigned int ek[EQCAP];
    __shared__ int ei[EQCAP];
    __shared__ int out_idx[K];
    __shared__ float out_tanh[K];
    int tid = threadIdx.x;
    int task = blockIdx.x;
    int* cg = cnts_b + task * 2;
    int g = cg[0];
    int m = min(cg[1], EQCAP);
    int need = K - g;
    const int* gt_idx = gt_idx_b + task * 128;
    const float* gt_val = gt_val_b + task * 128;
    const int* eq_idx = eq_idx_b + task * EQCAP;
    const float* eq_val = eq_val_b + task * EQCAP;
    const float* X = X_b + (size_t)task * N * FIN;
    float* z = z_b + (size_t)task * FIN * K;

    for (int i = tid; i < g; i += 1024) { sidx[i] = gt_idx[i]; sval[i] = gt_val[i]; }
    for (int i = tid; i < m; i += 1024) { ek[i] = key_of(eq_val[i]); ei[i] = eq_idx[i]; }
    __syncthreads();
    for (int i = tid; i < m; i += 1024) {
        int myi = ei[i];
        unsigned int myk = ek[i];
        int rank = 0;
        for (int j = 0; j < m; j++)
            rank += (ek[j] > myk) || (ek[j] == myk && ei[j] < myi);
        if (rank < need) { sidx[g + rank] = myi; sval[g + rank] = eq_val[i]; }
    }
    __syncthreads();
    if (tid < K) {
        float v = sval[tid];
        int id = sidx[tid];
        unsigned int myk = key_of(v);
        int rank = 0;
        for (int j = 0; j < K; j++) {
            unsigned int kj = key_of(sval[j]);
            rank += (kj > myk) || (kj == myk && sidx[j] < id);
        }
        out_idx[rank] = id;
        out_tanh[rank] = tanhf(v);
    }
    // self-zero for reuse (cnts slots shared between L0 and L1 passes)
    int* gh = ghist_b + (size_t)task * NBINS;
    for (int i = tid; i < NBINS; i += 1024) gh[i] = 0;
    if (tid == 0) { cg[0] = 0; cg[1] = 0; }
    __syncthreads();
    for (int i = tid; i < K * FIN; i += 1024) {
        int j = i >> 7;        // / FIN
        int r = i & 127;       // % FIN
        z[r * K + j] = X[(size_t)out_idx[j] * FIN + r] * out_tanh[j];
    }
}

// ---------------- multi-step fused GRU: all T steps in one kernel ----------------
template <int COLS>
__global__ void __launch_bounds__(256)
gru_multi_kernel(const float* __restrict__ Qinit, const float* __restrict__ z_all,
                 const float* __restrict__ Wu, const float* __restrict__ Uu, const float* __restrict__ Bu,
                 const float* __restrict__ Wr, const float* __restrict__ Ur, const float* __restrict__ Br,
                 const float* __restrict__ Wh, const float* __restrict__ Uh, const float* __restrict__ Bh,
                 float* __restrict__ Qn_all) {
    __shared__ float zc[128][8];
    __shared__ float qc[128][8];
    __shared__ float rq[128][8];
    __shared__ float ul[128][8];
    int tid = threadIdx.x;
    int c0 = blockIdx.x * 8;
    for (int i = tid; i < 1024; i += 256) {
        int r = i >> 3, c = i & 7;
        qc[r][c] = Qinit[r * COLS + c0 + c];
    }
    for (int t = 0; t < T_STEPS; t++) {
        __syncthreads();   // protect zc (prev step readers) + publish qc updates
        const float* z = z_all + (size_t)t * 128 * COLS;
        for (int i = tid; i < 1024; i += 256) {
            int r = i >> 3, c = i & 7;
            zc[r][c] = z[r * COLS + c0 + c];
        }
        __syncthreads();
#pragma unroll
        for (int e = 0; e < 4; e++) {
            int idx = tid + 256 * e;
            int r = idx >> 3, c = idx & 7;
            float au = Bu[r * COLS + c0 + c], ar = Br[r * COLS + c0 + c];
            for (int k = 0; k < 128; k++) {
                float zz = zc[k][c], qq = qc[k][c];
                au += Wu[r * 128 + k] * zz + Uu[r * 128 + k] * qq;
                ar += Wr[r * 128 + k] * zz + Ur[r * 128 + k] * qq;
            }
            ul[r][c] = sigmoidf_(au);
            rq[r][c] = sigmoidf_(ar) * qc[r][c];
        }
        __syncthreads();
        float* Qn = Qn_all + (size_t)t * 128 * COLS;
#pragma unroll
        for (int e = 0; e < 4; e++) {
            int idx = tid + 256 * e;
            int r = idx >> 3, c = idx & 7;
            float s = Bh[r * COLS + c0 + c];
            for (int k = 0; k < 128; k++) {
                s += Wh[r * 128 + k] * zc[k][c] + Uh[r * 128 + k] * rq[k][c];
            }
            float h = tanhf(s);
            float u = ul[r][c];
            float qn = (1.f - u) * qc[r][c] + u * h;
            Qn[r * COLS + c0 + c] = qn;
            qc[r][c] = qn;     // own element only; published at next loop-top barrier
        }
    }
}

// ---------------- XW(t) = X(t) @ Qn(t) -> fp32 or bf16, batched over t via blockIdx.y ----------------
template <int COLS, bool BF16>
__global__ void __launch_bounds__(256)
xw_kernel(const float* __restrict__ X_b, const float* __restrict__ Qn_all,
          void* __restrict__ outp, int N) {
    constexpr int TPR = COLS / 4;
    constexpr int RPG = 256 / TPR;
    constexpr int RPB = RPG * 4;
    int t = blockIdx.y;
    const float* X = X_b + (size_t)t * N * FIN;
    const float* Qn = Qn_all + (size_t)t * 128 * COLS;
    __shared__ float4 qs[128 * TPR];
    for (int i = threadIdx.x; i < 128 * TPR; i += 256) qs[i] = ((const float4*)Qn)[i];
    __syncthreads();
    int lane_c = threadIdx.x % TPR;
    int rloc = threadIdx.x / TPR;
    int base = blockIdx.x * RPB;
    int rows[4];
    float4 acc[4];
#pragma unroll
    for (int j = 0; j < 4; j++) {
        rows[j] = base + rloc + j * RPG;
        acc[j] = make_float4(0.f, 0.f, 0.f, 0.f);
    }
    int nc[4];
#pragma unroll
    for (int j = 0; j < 4; j++) nc[j] = min(rows[j], N - 1);

    for (int k4 = 0; k4 < 32; k4++) {
        float4 q0 = qs[(k4 * 4 + 0) * TPR + lane_c];
        float4 q1 = qs[(k4 * 4 + 1) * TPR + lane_c];
        float4 q2 = qs[(k4 * 4 + 2) * TPR + lane_c];
        float4 q3 = qs[(k4 * 4 + 3) * TPR + lane_c];
#pragma unroll
        for (int j = 0; j < 4; j++) {
            float4 xv = ((const float4*)(X + (size_t)nc[j] * FIN))[k4];
            acc[j].x += xv.x * q0.x + xv.y * q1.x + xv.z * q2.x + xv.w * q3.x;
            acc[j].y += xv.x * q0.y + xv.y * q1.y + xv.z * q2.y + xv.w * q3.y;
            acc[j].z += xv.x * q0.z + xv.y * q1.z + xv.z * q2.z + xv.w * q3.z;
            acc[j].w += xv.x * q0.w + xv.y * q1.w + xv.z * q2.w + xv.w * q3.w;
        }
    }
#pragma unroll
    for (int j = 0; j < 4; j++) {
        if (rows[j] < N) {
            if (BF16) {
                ushort4 o;
                o.x = f2bf(acc[j].x); o.y = f2bf(acc[j].y);
                o.z = f2bf(acc[j].z); o.w = f2bf(acc[j].w);
                ((ushort4*)((unsigned short*)outp + ((size_t)t * N + rows[j]) * COLS))[lane_c] = o;
            } else {
                ((float4*)((float*)outp + ((size_t)t * N + rows[j]) * COLS))[lane_c] = acc[j];
            }
        }
    }
}

// ---------------- batched CSR build sorted by (t, src_shard, dst) ----------------
// 8 src-shards of DSHARD nodes each; counter idx = (t*8 + s)*N + dst
__global__ void hist8_kernel(const int* __restrict__ src, const int* __restrict__ dst,
                             int* __restrict__ hist8, int E) {
    int e = blockIdx.x * blockDim.x + threadIdx.x;
    if (e >= E) return;
    int t = blockIdx.y;
    size_t ge = (size_t)t * E + e;
    int s = src[ge] / DSHARD;
    atomicAdd(&hist8[(t * 8 + s) * NNODES + dst[ge]], 1);
}

__global__ void __launch_bounds__(256)
scanA_kernel(const int* __restrict__ hist, int* __restrict__ incl, int* __restrict__ bsum, int M) {
    __shared__ int sh[256];
    int gid = blockIdx.x * 256 + threadIdx.x;
    int v = (gid < M) ? hist[gid] : 0;
    sh[threadIdx.x] = v;
    __syncthreads();
    for (int off = 1; off < 256; off <<= 1) {
        int u = (threadIdx.x >= off) ? sh[threadIdx.x - off] : 0;
        __syncthreads();
        sh[threadIdx.x] += u;
        __syncthreads();
    }
    if (gid < M) incl[gid] = sh[threadIdx.x];
    if (threadIdx.x == 255) bsum[blockIdx.x] = sh[255];
}

__global__ void __launch_bounds__(1024)
scanB_kernel(int* __restrict__ bsum, int nb) {
    __shared__ int sh[1024];
    int tid = threadIdx.x;
    int v = (tid < nb) ? bsum[tid] : 0;
    sh[tid] = v;
    __syncthreads();
    for (int off = 1; off < 1024; off <<= 1) {
        int u = (tid >= off) ? sh[tid - off] : 0;
        __syncthreads();
        sh[tid] += u;
        __syncthreads();
    }
    if (tid < nb) bsum[tid] = (tid == 0) ? 0 : sh[tid - 1];
}

// two-level combine: exclusive(gid) = inclA[gid]-hist[gid] + (inclB[b]-bsumA[b]) + bsumB[b>>8]
__global__ void __launch_bounds__(256)
scanC2_kernel(const int* __restrict__ hist, const int* __restrict__ inclA,
              const int* __restrict__ bsumA, const int* __restrict__ inclB,
              const int* __restrict__ bsumB, int* __restrict__ row_ptr,
              int* __restrict__ cursor, int M) {
    int gid = blockIdx.x * 256 + threadIdx.x;
    if (gid < M) {
        int b = gid >> 8;
        int exBlock = inclB[b] - bsumA[b] + bsumB[b >> 8];
        int inc = inclA[gid] + exBlock;
        int ex = inc - hist[gid];
        row_ptr[gid] = ex;
        cursor[gid] = ex;
        if (gid == M - 1) row_ptr[M] = inc;
    }
}

// src-shard-sharded scatter: each block handles one src-shard so sedge writes stay
// within one (t,s) window (~400KB) -> lines coalesce (R7-style sharding, key flipped to src)
__global__ void bucket8_kernel(const int* __restrict__ src, const int* __restrict__ dst,
                               const float* __restrict__ w, int* __restrict__ cursor,
                               int2* __restrict__ sedge, int E) {
    int bx = blockIdx.x;
    int shard = bx & 7;
    int e = (bx >> 3) * 256 + threadIdx.x;
    if (e >= E) return;
    int t = blockIdx.y;
    size_t ge = (size_t)t * E + e;
    int sc = src[ge];
    if (sc / DSHARD != shard) return;
    int d = dst[ge];
    int pos = atomicAdd(&cursor[(t * 8 + shard) * NNODES + d], 1);
    int2 pk;
    pk.x = sc;
    pk.y = __float_as_int(w[ge]);
    sedge[pos] = pk;
}

// ---------------- CSR aggregation, src-shard phased for L2 locality ----------------
// 1D grid; xcd = blockIdx&7 picks t (2 XCDs per t) so each XCD's hot gather window is
// one 3.2MB (L0) / 0.8MB (L1) src-shard of one timestep -> fits 4MB per-XCD L2.
// out(t)[d] = relu(sum_s sum_{e in (t,s,d)} w_e * XW(t)[src_e]); SCORE emits L1 scores+hist.
template <int COLS, bool SCORE, bool BF16>
__global__ void __launch_bounds__(256)
agg_kernel(const void* __restrict__ XWp, const int* __restrict__ rp8,
           const int2* __restrict__ sedge,
           float* __restrict__ out_b, int N,
           const float* __restrict__ scorer, const float* __restrict__ norms,
           const float* __restrict__ mask_b, float* __restrict__ scores_b, int* __restrict__ ghist_b) {
    constexpr int TPN = COLS / 4;
    constexpr int NPB = 256 / TPN;
    int lin = blockIdx.x;
    int xcd = lin & 7;
    int slot = lin >> 3;
    int t = xcd >> 1;                 // XCDs {0,1}->t0, {2,3}->t1, ...
    int db = slot * 2 + (xcd & 1);
    int dstBlocks = (N + NPB - 1) / NPB;
    if (db >= dstBlocks) return;
    int node = db * NPB + threadIdx.x / TPN;   // N divisible by NPB for both layers
    int lane = threadIdx.x % TPN;
    size_t xwoff = (size_t)t * N * COLS;
    float4 a0 = make_float4(0.f, 0.f, 0.f, 0.f);
    float4 a1 = a0, a2 = a0, a3 = a0;
#pragma unroll 1
    for (int s = 0; s < 8; s++) {
        size_t ridx = (size_t)(t * 8 + s) * N + node;
        int i = rp8[ridx];
        int end = rp8[ridx + 1];
        for (; i + 4 <= end; i += 4) {
            int2 p0 = sedge[i], p1 = sedge[i + 1], p2 = sedge[i + 2], p3 = sedge[i + 3];
            if (BF16) {
                const unsigned short* XW = (const unsigned short*)XWp + xwoff;
                ushort4 v0 = ((const ushort4*)(XW + (size_t)p0.x * COLS))[lane];
                ushort4 v1 = ((const ushort4*)(XW + (size_t)p1.x * COLS))[lane];
                ushort4 v2 = ((const ushort4*)(XW + (size_t)p2.x * COLS))[lane];
                ushort4 v3 = ((const ushort4*)(XW + (size_t)p3.x * COLS))[lane];
                float w0 = __int_as_float(p0.y), w1 = __int_as_float(p1.y);
                float w2 = __int_as_float(p2.y), w3 = __int_as_float(p3.y);
                a0.x += bf2f(v0.x) * w0; a0.y += bf2f(v0.y) * w0; a0.z += bf2f(v0.z) * w0; a0.w += bf2f(v0.w) * w0;
                a1.x += bf2f(v1.x) * w1; a1.y += bf2f(v1.y) * w1; a1.z += bf2f(v1.z) * w1; a1.w += bf2f(v1.w) * w1;
                a2.x += bf2f(v2.x) * w2; a2.y += bf2f(v2.y) * w2; a2.z += bf2f(v2.z) * w2; a2.w += bf2f(v2.w) * w2;
                a3.x += bf2f(v3.x) * w3; a3.y += bf2f(v3.y) * w3; a3.z += bf2f(v3.z) * w3; a3.w += bf2f(v3.w) * w3;
            } else {
                const float* XW = (const float*)XWp + xwoff;
                float4 v0 = ((const float4*)(XW + (size_t)p0.x * COLS))[lane];
                float4 v1 = ((const float4*)(XW + (size_t)p1.x * COLS))[lane];
                float4 v2 = ((const float4*)(XW + (size_t)p2.x * COLS))[lane];
                float4 v3 = ((const float4*)(XW + (size_t)p3.x * COLS))[lane];
                float w0 = __int_as_float(p0.y), w1 = __int_as_float(p1.y);
                float w2 = __int_as_float(p2.y), w3 = __int_as_float(p3.y);
                a0.x += v0.x * w0; a0.y += v0.y * w0; a0.z += v0.z * w0; a0.w += v0.w * w0;
                a1.x += v1.x * w1; a1.y += v1.y * w1; a1.z += v1.z * w1; a1.w += v1.w * w1;
                a2.x += v2.x * w2; a2.y += v2.y * w2; a2.z += v2.z * w2; a2.w += v2.w * w2;
                a3.x += v3.x * w3; a3.y += v3.y * w3; a3.z += v3.z * w3; a3.w += v3.w * w3;
            }
        }
        for (; i < end; i++) {
            int2 pk = sedge[i];
            float wt = __int_as_float(pk.y);
            if (BF16) {
                const unsigned short* XW = (const unsigned short*)XWp + xwoff;
                ushort4 v = ((const ushort4*)(XW + (size_t)pk.x * COLS))[lane];
                a0.x += bf2f(v.x) * wt; a0.y += bf2f(v.y) * wt;
                a0.z += bf2f(v.z) * wt; a0.w += bf2f(v.w) * wt;
            } else {
                const float* XW = (const float*)XWp + xwoff;
                float4 v = ((const float4*)(XW + (size_t)pk.x * COLS))[lane];
                a0.x += v.x * wt; a0.y += v.y * wt; a0.z += v.z * wt; a0.w += v.w * wt;
            }
        }
        __syncthreads();   // keep block's threads phase-aligned on the hot shard
    }
    float4 acc;
    acc.x = (a0.x + a1.x) + (a2.x + a3.x);
    acc.y = (a0.y + a1.y) + (a2.y + a3.y);
    acc.z = (a0.z + a1.z) + (a2.z + a3.z);
    acc.w = (a0.w + a1.w) + (a2.w + a3.w);
    acc.x = fmaxf(acc.x, 0.f); acc.y = fmaxf(acc.y, 0.f);
    acc.z = fmaxf(acc.z, 0.f); acc.w = fmaxf(acc.w, 0.f);
    ((float4*)(out_b + ((size_t)t * N + node) * COLS))[lane] = acc;
    if (SCORE) {
        float4 sc4 = ((const float4*)scorer)[lane];
        float partial = acc.x * sc4.x + acc.y * sc4.y + acc.z * sc4.z + acc.w * sc4.w;
#pragma unroll
        for (int off = TPN / 2; off > 0; off >>= 1) partial += __shfl_xor(partial, off, TPN);
        if (lane == 0) {
            float s = partial / norms[1] + mask_b[(size_t)t * N + node];
            scores_b[(size_t)t * N + node] = s;
            atomicAdd(&ghist_b[t * NBINS + (key_of(s) >> BINSHIFT)], 1);
        }
    }
}

extern "C" void kernel_launch(void* const* d_in, const int* in_sizes, int n_in,
                              void* d_out, int out_size, void* d_ws, size_t ws_size,
                              hipStream_t stream) {
    const float* node_embs   = (const float*)d_in[0];
    const float* mask        = (const float*)d_in[1];
    const int*   edge_src    = (const int*)d_in[2];
    const int*   edge_dst    = (const int*)d_in[3];
    const float* edge_weight = (const float*)d_in[4];
    const float* gcn_w0      = (const float*)d_in[5];
    const float* gcn_w1      = (const float*)d_in[6];
    const float* l0p[10];
    const float* l1p[10];
    for (int i = 0; i < 10; i++) l0p[i] = (const float*)d_in[7 + i];
    for (int i = 0; i < 10; i++) l1p[i] = (const float*)d_in[17 + i];
    // l*p: 0=Wu 1=Uu 2=Bu 3=Wr 4=Ur 5=Br 6=Wh 7=Uh 8=Bh 9=scorer

    char* ws = (char*)d_ws;
    size_t off = 0;
    auto alloc = [&](size_t bytes) -> void* {
        void* p = ws + off;
        off += (bytes + 255) / 256 * 256;
        return p;
    };
    float* XW0buf = (float*)alloc((size_t)4 * NNODES * 128 * 4);          // fp32, all t (102 MB)
    float* h1buf  = (float*)alloc((size_t)4 * NNODES * 128 * 4);          // fp32, all t (102 MB)
    unsigned short* XW1buf = (unsigned short*)alloc((size_t)4 * NNODES * 64 * 2);  // bf16, all t
    float* scores4= (float*)alloc((size_t)4 * NNODES * 4);                // L0 scores (all t)
    float* scores1= (float*)alloc((size_t)4 * NNODES * 4);                // L1 scores (all t)
    float* z0buf  = (float*)alloc((size_t)4 * 128 * 128 * 4);
    float* z1buf  = (float*)alloc((size_t)4 * 128 * 64 * 4);
    float* Q0n    = (float*)alloc((size_t)4 * 128 * 128 * 4);
    float* Q1n    = (float*)alloc((size_t)4 * 128 * 64 * 4);
    float* norms  = (float*)alloc(64);
    const int M8 = 32 * NNODES;   // (t, src_shard, dst) counters: 1.6M
    // combined zeroed region: hist8[M8] + ghist0[4*NBINS] + ghist1[4*NBINS] + cnts[64]
    int* hist8    = (int*)alloc(((size_t)M8 + 8 * NBINS + 64) * 4);
    int* ghist0   = hist8 + M8;
    int* ghist1   = ghist0 + 4 * NBINS;
    int* cnts     = ghist1 + 4 * NBINS;
    int* inclA    = (int*)alloc((size_t)M8 * 4);
    int* bsumA    = (int*)alloc(8192 * 4);
    int* inclB    = (int*)alloc(8192 * 4);
    int* bsumB    = (int*)alloc(1024 * 4);
    int* rowp8    = (int*)alloc(((size_t)M8 + 1) * 4);
    int* cursor8  = (int*)alloc((size_t)M8 * 4);
    int2* sedge4  = (int2*)alloc((size_t)4 * NEDGES * 8);
    int*   gt_idx = (int*)alloc((size_t)4 * 128 * 4);
    float* gt_val = (float*)alloc((size_t)4 * 128 * 4);
    int*   eq_idx = (int*)alloc((size_t)4 * EQCAP * 4);
    float* eq_val = (float*)alloc((size_t)4 * EQCAP * 4);

    hipMemsetAsync(hist8, 0, ((size_t)M8 + 8 * NBINS + 64) * 4, stream);
    norm_kernel<<<1, 128, 0, stream>>>(l0p[9], l1p[9], norms);

    const int NB = (NNODES + 255) / 256;       // 196
    const int EB = (NEDGES + 255) / 256;       // 1563
    const int NB8  = (M8 + 255) / 256;         // 6250 (level-1 scan blocks)
    const int NB8b = (NB8 + 255) / 256;        // 25   (level-2 scan blocks)

    // ---- batched CSR build sorted by (t, src_shard, dst) ----
    hist8_kernel<<<dim3(EB, 4), 256, 0, stream>>>(edge_src, edge_dst, hist8, NEDGES);
    scanA_kernel<<<NB8, 256, 0, stream>>>(hist8, inclA, bsumA, M8);
    scanA_kernel<<<NB8b, 256, 0, stream>>>(bsumA, inclB, bsumB, NB8);
    scanB_kernel<<<1, 1024, 0, stream>>>(bsumB, NB8b);
    scanC2_kernel<<<NB8, 256, 0, stream>>>(hist8, inclA, bsumA, inclB, bsumB, rowp8, cursor8, M8);
    bucket8_kernel<<<dim3(EB * 8, 4), 256, 0, stream>>>(edge_src, edge_dst, edge_weight, cursor8, sedge4, NEDGES);

    // ---- L0: scores + top-k + z for ALL t (input-only dependence) ----
    scores_hist4_kernel<<<dim3(NB, 4), 256, 0, stream>>>(node_embs, l0p[9], norms, mask, scores4, ghist0, NNODES);
    topk_collect_kernel<<<dim3(NB, 4), 256, 0, stream>>>(scores4, ghist0, cnts, gt_idx, gt_val, eq_idx, eq_val, NNODES, 128);
    topk_finish_kernel<128><<<4, 1024, 0, stream>>>(ghist0, cnts, gt_idx, gt_val, eq_idx, eq_val, node_embs, z0buf, NNODES);

    // ---- L0 GRU recurrence (all t, one kernel), then batched XW + agg ----
    gru_multi_kernel<128><<<16, 256, 0, stream>>>(gcn_w0, z0buf,
        l0p[0], l0p[1], l0p[2], l0p[3], l0p[4], l0p[5], l0p[6], l0p[7], l0p[8], Q0n);
    xw_kernel<128, false><<<dim3((NNODES + 31) / 32, 4), 256, 0, stream>>>(node_embs, Q0n, XW0buf, NNODES);
    {
        const int dstBlocks0 = (NNODES + 7) / 8;            // 6250 (NPB=8 for COLS=128)
        const int grid0 = ((dstBlocks0 + 1) / 2) * 8;       // 25000
        agg_kernel<128, true, false><<<grid0, 256, 0, stream>>>(XW0buf, rowp8, sedge4, h1buf, NNODES,
            l1p[9], norms, mask, scores1, ghist1);
    }

    // ---- L1: top-k for all t (h1+scores1 ready), GRU recurrence, batched XW + agg -> d_out ----
    topk_collect_kernel<<<dim3(NB, 4), 256, 0, stream>>>(scores1, ghist1, cnts, gt_idx, gt_val, eq_idx, eq_val, NNODES, 64);
    topk_finish_kernel<64><<<4, 1024, 0, stream>>>(ghist1, cnts, gt_idx, gt_val, eq_idx, eq_val, h1buf, z1buf, NNODES);
    gru_multi_kernel<64><<<8, 256, 0, stream>>>(gcn_w1, z1buf,
        l1p[0], l1p[1], l1p[2], l1p[3], l1p[4], l1p[5], l1p[6], l1p[7], l1p[8], Q1n);
    xw_kernel<64, true><<<dim3((NNODES + 63) / 64, 4), 256, 0, stream>>>(h1buf, Q1n, XW1buf, NNODES);
    {
        const int dstBlocks1 = (NNODES + 15) / 16;          // 3125 (NPB=16 for COLS=64)
        const int grid1 = ((dstBlocks1 + 1) / 2) * 8;       // 12504
        agg_kernel<64, false, true><<<grid1, 256, 0, stream>>>(XW1buf, rowp8, sedge4, (float*)d_out, NNODES,
            nullptr, nullptr, nullptr, nullptr, nullptr);
    }
}

// Round 4
// 1190.740 us; speedup vs baseline: 1.1122x; 1.1122x over previous
//
#include <hip/hip_runtime.h>
#include <math.h>

#define T_STEPS 4
#define NNODES 50000
#define NEDGES 400000
#define FIN 128   // input feature dim for both layers
#define NBINS 8192
#define BINSHIFT 19  // 32-13
#define EQCAP 4096
#define DSHARD 6250  // NNODES/8

__device__ __forceinline__ float sigmoidf_(float x) { return 1.0f / (1.0f + __expf(-x)); }

__device__ __forceinline__ unsigned int key_of(float s) {
    unsigned int u = __float_as_uint(s);
    return (u & 0x80000000u) ? ~u : (u | 0x80000000u);
}

__device__ __forceinline__ unsigned short f2bf(float f) {
    unsigned int u = __float_as_uint(f);
    unsigned int r = (u + 0x7FFFu + ((u >> 16) & 1u)) >> 16;
    return (unsigned short)r;
}
__device__ __forceinline__ float bf2f(unsigned short h) {
    return __uint_as_float(((unsigned int)h) << 16);
}

typedef float f4v __attribute__((ext_vector_type(4)));
__device__ __forceinline__ void nt_store4(float* p, float4 v) {
    f4v w; w.x = v.x; w.y = v.y; w.z = v.z; w.w = v.w;
    __builtin_nontemporal_store(w, (f4v*)p);
}

// ---------------- norms of the two scorers ----------------
__global__ void norm_kernel(const float* __restrict__ s0, const float* __restrict__ s1,
                            float* __restrict__ norms) {
    __shared__ float red[128];
    int tid = threadIdx.x;  // 128 threads
    float a = s0[tid];
    red[tid] = a * a;
    __syncthreads();
    for (int off = 64; off > 0; off >>= 1) { if (tid < off) red[tid] += red[tid + off]; __syncthreads(); }
    if (tid == 0) norms[0] = sqrtf(red[0]);
    __syncthreads();
    float b = s1[tid];
    red[tid] = b * b;
    __syncthreads();
    for (int off = 64; off > 0; off >>= 1) { if (tid < off) red[tid] += red[tid + off]; __syncthreads(); }
    if (tid == 0) norms[1] = sqrtf(red[0]);
}

// ---------------- L0 scores for ALL t + topk histogram ----------------
// grid: (ceil(N/256), T_STEPS)
__global__ void scores_hist4_kernel(const float* __restrict__ node_embs, const float* __restrict__ scorer,
                                    const float* __restrict__ norms,
                                    const float* __restrict__ mask, float* __restrict__ scores4,
                                    int* __restrict__ ghist4, int N) {
    __shared__ float sc[FIN];
    if (threadIdx.x < FIN) sc[threadIdx.x] = scorer[threadIdx.x];
    __syncthreads();
    int t = blockIdx.y;
    int n = blockIdx.x * blockDim.x + threadIdx.x;
    if (n >= N) return;
    const float4* xr = (const float4*)(node_embs + ((size_t)t * N + n) * FIN);
    float acc = 0.f;
#pragma unroll 8
    for (int k4 = 0; k4 < FIN / 4; k4++) {
        float4 v = xr[k4];
        acc += v.x * sc[k4 * 4] + v.y * sc[k4 * 4 + 1] + v.z * sc[k4 * 4 + 2] + v.w * sc[k4 * 4 + 3];
    }
    float s = acc / norms[0] + mask[(size_t)t * N + n];
    scores4[(size_t)t * N + n] = s;
    atomicAdd(&ghist4[t * NBINS + (key_of(s) >> BINSHIFT)], 1);
}

// ---------------- parallel top-k collect: each block re-derives critical bin ----------------
// grid: (196, ntasks). task strides: scores N, ghist NBINS, cnts 2, gt 128, eq EQCAP
__global__ void __launch_bounds__(256)
topk_collect_kernel(const float* __restrict__ scores_b, const int* __restrict__ ghist_b,
                    int* __restrict__ cnts_b, int* __restrict__ gt_idx_b, float* __restrict__ gt_val_b,
                    int* __restrict__ eq_idx_b, float* __restrict__ eq_val_b, int N, int K) {
    __shared__ int h[NBINS];
    __shared__ int part[256];
    __shared__ int s_bin;
    int tid = threadIdx.x;
    int task = blockIdx.y;
    const int* gh = ghist_b + (size_t)task * NBINS;
    for (int i = tid; i < NBINS; i += 256) h[i] = gh[i];
    __syncthreads();
    int s = 0;
#pragma unroll
    for (int i = 0; i < NBINS / 256; i++) s += h[tid * (NBINS / 256) + i];
    part[tid] = s;
    __syncthreads();
    for (int off = 1; off < 256; off <<= 1) {
        int v = (tid + off < 256) ? part[tid + off] : 0;
        __syncthreads();
        part[tid] += v;
        __syncthreads();
    }
    {
        int run = (tid == 255) ? 0 : part[tid + 1];
        const int CH = NBINS / 256;
        for (int b = tid * CH + CH - 1; b >= tid * CH; b--) {
            int Sb = run + h[b];
            if (Sb >= K && run < K) s_bin = b;
            run = Sb;
        }
    }
    __syncthreads();
    int bin = s_bin;
    const float* scores = scores_b + (size_t)task * N;
    int* cg = cnts_b + task * 2;
    for (int n = blockIdx.x * 256 + tid; n < N; n += gridDim.x * 256) {
        float sc = scores[n];
        unsigned int key = key_of(sc);
        int kb = (int)(key >> BINSHIFT);
        if (kb > bin) {
            int p = atomicAdd(&cg[0], 1);
            gt_idx_b[task * 128 + p] = n; gt_val_b[task * 128 + p] = sc;
        } else if (kb == bin) {
            int p = atomicAdd(&cg[1], 1);
            if (p < EQCAP) { eq_idx_b[task * EQCAP + p] = n; eq_val_b[task * EQCAP + p] = sc; }
        }
    }
}

// ---------------- finish: exact rank + sort + z build; self-zero ghist & cnts ----------------
// grid: (ntasks). need = K - cnt_gt. z[r*K+j] = X[idx_j*FIN+r]*tanh(val_j)
template <int K>
__global__ void __launch_bounds__(1024)
topk_finish_kernel(int* __restrict__ ghist_b, int* __restrict__ cnts_b,
                   const int* __restrict__ gt_idx_b, const float* __restrict__ gt_val_b,
                   const int* __restrict__ eq_idx_b, const float* __restrict__ eq_val_b,
                   const float* __restrict__ X_b, float* __restrict__ z_b, int N) {
    __shared__ int sidx[K];
    __shared__ float sval[K];
    __shared__ unsigned int ek[EQCAP];
    __shared__ int ei[EQCAP];
    __shared__ int out_idx[K];
    __shared__ float out_tanh[K];
    int tid = threadIdx.x;
    int task = blockIdx.x;
    int* cg = cnts_b + task * 2;
    int g = cg[0];
    int m = min(cg[1], EQCAP);
    int need = K - g;
    const int* gt_idx = gt_idx_b + task * 128;
    const float* gt_val = gt_val_b + task * 128;
    const int* eq_idx = eq_idx_b + task * EQCAP;
    const float* eq_val = eq_val_b + task * EQCAP;
    const float* X = X_b + (size_t)task * N * FIN;
    float* z = z_b + (size_t)task * FIN * K;

    for (int i = tid; i < g; i += 1024) { sidx[i] = gt_idx[i]; sval[i] = gt_val[i]; }
    for (int i = tid; i < m; i += 1024) { ek[i] = key_of(eq_val[i]); ei[i] = eq_idx[i]; }
    __syncthreads();
    for (int i = tid; i < m; i += 1024) {
        int myi = ei[i];
        unsigned int myk = ek[i];
        int rank = 0;
        for (int j = 0; j < m; j++)
            rank += (ek[j] > myk) || (ek[j] == myk && ei[j] < myi);
        if (rank < need) { sidx[g + rank] = myi; sval[g + rank] = eq_val[i]; }
    }
    __syncthreads();
    if (tid < K) {
        float v = sval[tid];
        int id = sidx[tid];
        unsigned int myk = key_of(v);
        int rank = 0;
        for (int j = 0; j < K; j++) {
            unsigned int kj = key_of(sval[j]);
            rank += (kj > myk) || (kj == myk && sidx[j] < id);
        }
        out_idx[rank] = id;
        out_tanh[rank] = tanhf(v);
    }
    // self-zero for reuse (cnts slots shared between L0 and L1 passes)
    int* gh = ghist_b + (size_t)task * NBINS;
    for (int i = tid; i < NBINS; i += 1024) gh[i] = 0;
    if (tid == 0) { cg[0] = 0; cg[1] = 0; }
    __syncthreads();
    for (int i = tid; i < K * FIN; i += 1024) {
        int j = i >> 7;        // / FIN
        int r = i & 127;       // % FIN
        z[r * K + j] = X[(size_t)out_idx[j] * FIN + r] * out_tanh[j];
    }
}

// ---------------- multi-step fused GRU: all T steps in one kernel ----------------
// Column-separable recurrence: block owns 8 columns, holds Q in LDS across steps.
template <int COLS>
__global__ void __launch_bounds__(256)
gru_multi_kernel(const float* __restrict__ Qinit, const float* __restrict__ z_all,
                 const float* __restrict__ Wu, const float* __restrict__ Uu, const float* __restrict__ Bu,
                 const float* __restrict__ Wr, const float* __restrict__ Ur, const float* __restrict__ Br,
                 const float* __restrict__ Wh, const float* __restrict__ Uh, const float* __restrict__ Bh,
                 float* __restrict__ Qn_all) {
    __shared__ float zc[128][8];
    __shared__ float qc[128][8];
    __shared__ float rq[128][8];
    __shared__ float ul[128][8];
    int tid = threadIdx.x;
    int c0 = blockIdx.x * 8;
    for (int i = tid; i < 1024; i += 256) {
        int r = i >> 3, c = i & 7;
        qc[r][c] = Qinit[r * COLS + c0 + c];
    }
    for (int t = 0; t < T_STEPS; t++) {
        __syncthreads();   // protect zc (prev step readers) + publish qc updates
        const float* z = z_all + (size_t)t * 128 * COLS;
        for (int i = tid; i < 1024; i += 256) {
            int r = i >> 3, c = i & 7;
            zc[r][c] = z[r * COLS + c0 + c];
        }
        __syncthreads();
#pragma unroll
        for (int e = 0; e < 4; e++) {
            int idx = tid + 256 * e;
            int r = idx >> 3, c = idx & 7;
            float au = Bu[r * COLS + c0 + c], ar = Br[r * COLS + c0 + c];
            for (int k = 0; k < 128; k++) {
                float zz = zc[k][c], qq = qc[k][c];
                au += Wu[r * 128 + k] * zz + Uu[r * 128 + k] * qq;
                ar += Wr[r * 128 + k] * zz + Ur[r * 128 + k] * qq;
            }
            ul[r][c] = sigmoidf_(au);
            rq[r][c] = sigmoidf_(ar) * qc[r][c];
        }
        __syncthreads();
        float* Qn = Qn_all + (size_t)t * 128 * COLS;
#pragma unroll
        for (int e = 0; e < 4; e++) {
            int idx = tid + 256 * e;
            int r = idx >> 3, c = idx & 7;
            float s = Bh[r * COLS + c0 + c];
            for (int k = 0; k < 128; k++) {
                s += Wh[r * 128 + k] * zc[k][c] + Uh[r * 128 + k] * rq[k][c];
            }
            float h = tanhf(s);
            float u = ul[r][c];
            float qn = (1.f - u) * qc[r][c] + u * h;
            Qn[r * COLS + c0 + c] = qn;
            qc[r][c] = qn;     // own element only; published at next loop-top barrier
        }
    }
}

// ---------------- XW(t) = X(t) @ Qn(t) -> fp32 or bf16, batched over t via blockIdx.y ----------------
template <int COLS, bool BF16>
__global__ void __launch_bounds__(256)
xw_kernel(const float* __restrict__ X_b, const float* __restrict__ Qn_all,
          void* __restrict__ outp, int N) {
    constexpr int TPR = COLS / 4;
    constexpr int RPG = 256 / TPR;
    constexpr int RPB = RPG * 4;
    int t = blockIdx.y;
    const float* X = X_b + (size_t)t * N * FIN;
    const float* Qn = Qn_all + (size_t)t * 128 * COLS;
    __shared__ float4 qs[128 * TPR];
    for (int i = threadIdx.x; i < 128 * TPR; i += 256) qs[i] = ((const float4*)Qn)[i];
    __syncthreads();
    int lane_c = threadIdx.x % TPR;
    int rloc = threadIdx.x / TPR;
    int base = blockIdx.x * RPB;
    int rows[4];
    float4 acc[4];
#pragma unroll
    for (int j = 0; j < 4; j++) {
        rows[j] = base + rloc + j * RPG;
        acc[j] = make_float4(0.f, 0.f, 0.f, 0.f);
    }
    int nc[4];
#pragma unroll
    for (int j = 0; j < 4; j++) nc[j] = min(rows[j], N - 1);

    for (int k4 = 0; k4 < 32; k4++) {
        float4 q0 = qs[(k4 * 4 + 0) * TPR + lane_c];
        float4 q1 = qs[(k4 * 4 + 1) * TPR + lane_c];
        float4 q2 = qs[(k4 * 4 + 2) * TPR + lane_c];
        float4 q3 = qs[(k4 * 4 + 3) * TPR + lane_c];
#pragma unroll
        for (int j = 0; j < 4; j++) {
            float4 xv = ((const float4*)(X + (size_t)nc[j] * FIN))[k4];
            acc[j].x += xv.x * q0.x + xv.y * q1.x + xv.z * q2.x + xv.w * q3.x;
            acc[j].y += xv.x * q0.y + xv.y * q1.y + xv.z * q2.y + xv.w * q3.y;
            acc[j].z += xv.x * q0.z + xv.y * q1.z + xv.z * q2.z + xv.w * q3.z;
            acc[j].w += xv.x * q0.w + xv.y * q1.w + xv.z * q2.w + xv.w * q3.w;
        }
    }
#pragma unroll
    for (int j = 0; j < 4; j++) {
        if (rows[j] < N) {
            if (BF16) {
                ushort4 o;
                o.x = f2bf(acc[j].x); o.y = f2bf(acc[j].y);
                o.z = f2bf(acc[j].z); o.w = f2bf(acc[j].w);
                ((ushort4*)((unsigned short*)outp + ((size_t)t * N + rows[j]) * COLS))[lane_c] = o;
            } else {
                ((float4*)((float*)outp + ((size_t)t * N + rows[j]) * COLS))[lane_c] = acc[j];
            }
        }
    }
}

// ---------------- batched CSR build over all 4 timesteps (sorted by (t,dst)) ----------------
__global__ void hist4_kernel(const int* __restrict__ dst, int* __restrict__ hist4, int E) {
    int e = blockIdx.x * blockDim.x + threadIdx.x;
    if (e >= E) return;
    int t = blockIdx.y;
    atomicAdd(&hist4[t * NNODES + dst[(size_t)t * E + e]], 1);
}

__global__ void __launch_bounds__(256)
scanA_kernel(const int* __restrict__ hist, int* __restrict__ incl, int* __restrict__ bsum, int M) {
    __shared__ int sh[256];
    int gid = blockIdx.x * 256 + threadIdx.x;
    int v = (gid < M) ? hist[gid] : 0;
    sh[threadIdx.x] = v;
    __syncthreads();
    for (int off = 1; off < 256; off <<= 1) {
        int u = (threadIdx.x >= off) ? sh[threadIdx.x - off] : 0;
        __syncthreads();
        sh[threadIdx.x] += u;
        __syncthreads();
    }
    if (gid < M) incl[gid] = sh[threadIdx.x];
    if (threadIdx.x == 255) bsum[blockIdx.x] = sh[255];
}

__global__ void __launch_bounds__(1024)
scanB_kernel(int* __restrict__ bsum, int nb) {
    __shared__ int sh[1024];
    int tid = threadIdx.x;
    int v = (tid < nb) ? bsum[tid] : 0;
    sh[tid] = v;
    __syncthreads();
    for (int off = 1; off < 1024; off <<= 1) {
        int u = (tid >= off) ? sh[tid - off] : 0;
        __syncthreads();
        sh[tid] += u;
        __syncthreads();
    }
    if (tid < nb) bsum[tid] = (tid == 0) ? 0 : sh[tid - 1];
}

__global__ void __launch_bounds__(256)
scanC_kernel(const int* __restrict__ hist, const int* __restrict__ incl,
             const int* __restrict__ bsum, int* __restrict__ row_ptr,
             int* __restrict__ cursor, int M) {
    int gid = blockIdx.x * 256 + threadIdx.x;
    if (gid < M) {
        int inc = incl[gid] + bsum[gid / 256];
        int ex = inc - hist[gid];
        row_ptr[gid] = ex;
        cursor[gid] = ex;
        if (gid == M - 1) row_ptr[M] = inc;
    }
}

// dst-range-sharded scatter (R7 win: keeps sedge writes XCD-local, lines coalesce)
__global__ void bucket4_kernel(const int* __restrict__ src, const int* __restrict__ dst,
                               const float* __restrict__ w, int* __restrict__ cursor,
                               int2* __restrict__ sedge, int E) {
    int bx = blockIdx.x;
    int shard = bx & 7;
    int e = (bx >> 3) * 256 + threadIdx.x;
    if (e >= E) return;
    int t = blockIdx.y;
    size_t ge = (size_t)t * E + e;
    int d = dst[ge];
    if (d / DSHARD != shard) return;
    int pos = atomicAdd(&cursor[t * NNODES + d], 1);
    int2 pk;
    pk.x = src[ge];
    pk.y = __float_as_int(w[ge]);
    sedge[pos] = pk;
}

// ---------------- L0 CSR aggregation, column-sliced: one launch per 32-col slice ----------------
// Each launch gathers exactly 1 cache line (128B) per edge from a 25.6MB chip-wide slice
// (6.4MB per t) -> L3-resident across the pass; launch boundary enforces phase alignment.
// Summation order per output element identical to the unsliced kernel (edge order unchanged).
// Scores accumulate across passes in scoreacc (one owner thread per (t,node) per pass).
template <int SW, bool SCORE>
__global__ void __launch_bounds__(256)
agg_slice_kernel(const float* __restrict__ XW_b, const int* __restrict__ row_ptr4,
                 const int2* __restrict__ sedge,
                 float* __restrict__ out_b, int N, int P,
                 const float* __restrict__ scorer, const float* __restrict__ norms,
                 const float* __restrict__ mask_b, float* __restrict__ scores_b,
                 int* __restrict__ ghist_b, float* __restrict__ scoreacc) {
    constexpr int TPN = SW / 4;        // 8 threads per node
    constexpr int NPB = 256 / TPN;     // 32 nodes per block
    constexpr int NPASS = FIN / SW;    // 4
    int lin = blockIdx.x;
    int xcd = lin & 7;
    int slot = lin >> 3;
    int t = xcd >> 1;                 // XCDs {0,1}->t0, {2,3}->t1, ...
    int db = slot * 2 + (xcd & 1);
    int dstBlocks = (N + NPB - 1) / NPB;
    if (db >= dstBlocks) return;
    int node = db * NPB + threadIdx.x / TPN;
    if (node >= N) return;
    int lane = threadIdx.x % TPN;
    const int* rp = row_ptr4 + (size_t)t * N;
    int beg = rp[node], end = rp[node + 1];
    const float* XW = XW_b + (size_t)t * N * FIN + P * SW;
    float4 a0 = make_float4(0.f, 0.f, 0.f, 0.f);
    float4 a1 = a0, a2 = a0, a3 = a0;
    int i = beg;
    for (; i + 4 <= end; i += 4) {
        int2 p0 = sedge[i], p1 = sedge[i + 1], p2 = sedge[i + 2], p3 = sedge[i + 3];
        float4 v0 = ((const float4*)(XW + (size_t)p0.x * FIN))[lane];
        float4 v1 = ((const float4*)(XW + (size_t)p1.x * FIN))[lane];
        float4 v2 = ((const float4*)(XW + (size_t)p2.x * FIN))[lane];
        float4 v3 = ((const float4*)(XW + (size_t)p3.x * FIN))[lane];
        float w0 = __int_as_float(p0.y), w1 = __int_as_float(p1.y);
        float w2 = __int_as_float(p2.y), w3 = __int_as_float(p3.y);
        a0.x += v0.x * w0; a0.y += v0.y * w0; a0.z += v0.z * w0; a0.w += v0.w * w0;
        a1.x += v1.x * w1; a1.y += v1.y * w1; a1.z += v1.z * w1; a1.w += v1.w * w1;
        a2.x += v2.x * w2; a2.y += v2.y * w2; a2.z += v2.z * w2; a2.w += v2.w * w2;
        a3.x += v3.x * w3; a3.y += v3.y * w3; a3.z += v3.z * w3; a3.w += v3.w * w3;
    }
    for (; i < end; i++) {
        int2 pk = sedge[i];
        float wt = __int_as_float(pk.y);
        float4 v = ((const float4*)(XW + (size_t)pk.x * FIN))[lane];
        a0.x += v.x * wt; a0.y += v.y * wt; a0.z += v.z * wt; a0.w += v.w * wt;
    }
    float4 acc;
    acc.x = (a0.x + a1.x) + (a2.x + a3.x);
    acc.y = (a0.y + a1.y) + (a2.y + a3.y);
    acc.z = (a0.z + a1.z) + (a2.z + a3.z);
    acc.w = (a0.w + a1.w) + (a2.w + a3.w);
    acc.x = fmaxf(acc.x, 0.f); acc.y = fmaxf(acc.y, 0.f);
    acc.z = fmaxf(acc.z, 0.f); acc.w = fmaxf(acc.w, 0.f);
    nt_store4(out_b + ((size_t)t * N + node) * FIN + P * SW + lane * 4, acc);
    if (SCORE) {
        float4 sc4 = ((const float4*)(scorer + P * SW))[lane];
        float partial = acc.x * sc4.x + acc.y * sc4.y + acc.z * sc4.z + acc.w * sc4.w;
#pragma unroll
        for (int off = TPN / 2; off > 0; off >>= 1) partial += __shfl_xor(partial, off, TPN);
        if (lane == 0) {
            float* sa = scoreacc + (size_t)t * N + node;
            float tot = (P == 0 ? 0.f : *sa) + partial;
            if (P == NPASS - 1) {
                float s = tot / norms[1] + mask_b[(size_t)t * N + node];
                scores_b[(size_t)t * N + node] = s;
                atomicAdd(&ghist_b[t * NBINS + (key_of(s) >> BINSHIFT)], 1);
            } else {
                *sa = tot;
            }
        }
    }
}

// ---------------- L1 CSR aggregation (bf16 gather, fp32 out) ----------------
// 1D grid; xcd = blockIdx&7 picks t (2 XCDs per t); per-t bf16 XW1 = 6.4MB.
template <int COLS>
__global__ void __launch_bounds__(256)
agg_kernel(const unsigned short* __restrict__ XWb, const int* __restrict__ row_ptr4,
           const int2* __restrict__ sedge,
           float* __restrict__ out_b, int N) {
    constexpr int TPN = COLS / 4;
    constexpr int NPB = 256 / TPN;
    int lin = blockIdx.x;
    int xcd = lin & 7;
    int slot = lin >> 3;
    int t = xcd >> 1;
    int db = slot * 2 + (xcd & 1);
    int dstBlocks = (N + NPB - 1) / NPB;
    if (db >= dstBlocks) return;
    int node = db * NPB + threadIdx.x / TPN;
    if (node >= N) return;
    int lane = threadIdx.x % TPN;
    const int* rp = row_ptr4 + (size_t)t * N;
    int beg = rp[node], end = rp[node + 1];
    const unsigned short* XW = XWb + (size_t)t * N * COLS;
    float4 a0 = make_float4(0.f, 0.f, 0.f, 0.f);
    float4 a1 = a0, a2 = a0, a3 = a0;
    int i = beg;
    for (; i + 4 <= end; i += 4) {
        int2 p0 = sedge[i], p1 = sedge[i + 1], p2 = sedge[i + 2], p3 = sedge[i + 3];
        ushort4 v0 = ((const ushort4*)(XW + (size_t)p0.x * COLS))[lane];
        ushort4 v1 = ((const ushort4*)(XW + (size_t)p1.x * COLS))[lane];
        ushort4 v2 = ((const ushort4*)(XW + (size_t)p2.x * COLS))[lane];
        ushort4 v3 = ((const ushort4*)(XW + (size_t)p3.x * COLS))[lane];
        float w0 = __int_as_float(p0.y), w1 = __int_as_float(p1.y);
        float w2 = __int_as_float(p2.y), w3 = __int_as_float(p3.y);
        a0.x += bf2f(v0.x) * w0; a0.y += bf2f(v0.y) * w0; a0.z += bf2f(v0.z) * w0; a0.w += bf2f(v0.w) * w0;
        a1.x += bf2f(v1.x) * w1; a1.y += bf2f(v1.y) * w1; a1.z += bf2f(v1.z) * w1; a1.w += bf2f(v1.w) * w1;
        a2.x += bf2f(v2.x) * w2; a2.y += bf2f(v2.y) * w2; a2.z += bf2f(v2.z) * w2; a2.w += bf2f(v2.w) * w2;
        a3.x += bf2f(v3.x) * w3; a3.y += bf2f(v3.y) * w3; a3.z += bf2f(v3.z) * w3; a3.w += bf2f(v3.w) * w3;
    }
    for (; i < end; i++) {
        int2 pk = sedge[i];
        float wt = __int_as_float(pk.y);
        ushort4 v = ((const ushort4*)(XW + (size_t)pk.x * COLS))[lane];
        a0.x += bf2f(v.x) * wt; a0.y += bf2f(v.y) * wt;
        a0.z += bf2f(v.z) * wt; a0.w += bf2f(v.w) * wt;
    }
    float4 acc;
    acc.x = (a0.x + a1.x) + (a2.x + a3.x);
    acc.y = (a0.y + a1.y) + (a2.y + a3.y);
    acc.z = (a0.z + a1.z) + (a2.z + a3.z);
    acc.w = (a0.w + a1.w) + (a2.w + a3.w);
    acc.x = fmaxf(acc.x, 0.f); acc.y = fmaxf(acc.y, 0.f);
    acc.z = fmaxf(acc.z, 0.f); acc.w = fmaxf(acc.w, 0.f);
    nt_store4(out_b + ((size_t)t * N + node) * COLS + lane * 4, acc);
}

extern "C" void kernel_launch(void* const* d_in, const int* in_sizes, int n_in,
                              void* d_out, int out_size, void* d_ws, size_t ws_size,
                              hipStream_t stream) {
    const float* node_embs   = (const float*)d_in[0];
    const float* mask        = (const float*)d_in[1];
    const int*   edge_src    = (const int*)d_in[2];
    const int*   edge_dst    = (const int*)d_in[3];
    const float* edge_weight = (const float*)d_in[4];
    const float* gcn_w0      = (const float*)d_in[5];
    const float* gcn_w1      = (const float*)d_in[6];
    const float* l0p[10];
    const float* l1p[10];
    for (int i = 0; i < 10; i++) l0p[i] = (const float*)d_in[7 + i];
    for (int i = 0; i < 10; i++) l1p[i] = (const float*)d_in[17 + i];
    // l*p: 0=Wu 1=Uu 2=Bu 3=Wr 4=Ur 5=Br 6=Wh 7=Uh 8=Bh 9=scorer

    char* ws = (char*)d_ws;
    size_t off = 0;
    auto alloc = [&](size_t bytes) -> void* {
        void* p = ws + off;
        off += (bytes + 255) / 256 * 256;
        return p;
    };
    float* XW0buf = (float*)alloc((size_t)4 * NNODES * 128 * 4);          // fp32, all t (102 MB)
    float* h1buf  = (float*)alloc((size_t)4 * NNODES * 128 * 4);          // fp32, all t (102 MB)
    unsigned short* XW1buf = (unsigned short*)alloc((size_t)4 * NNODES * 64 * 2);  // bf16, all t
    float* scores4= (float*)alloc((size_t)4 * NNODES * 4);                // L0 scores (all t)
    float* scores1= (float*)alloc((size_t)4 * NNODES * 4);                // L1 scores (all t)
    float* scoreacc=(float*)alloc((size_t)4 * NNODES * 4);                // partial L1 score dots
    float* z0buf  = (float*)alloc((size_t)4 * 128 * 128 * 4);
    float* z1buf  = (float*)alloc((size_t)4 * 128 * 64 * 4);
    float* Q0n    = (float*)alloc((size_t)4 * 128 * 128 * 4);
    float* Q1n    = (float*)alloc((size_t)4 * 128 * 64 * 4);
    float* norms  = (float*)alloc(64);
    // combined zeroed region: hist4[4N] + ghist0[4*NBINS] + ghist1[4*NBINS] + cnts[64]
    int* hist4    = (int*)alloc(((size_t)4 * NNODES + 8 * NBINS + 64) * 4);
    int* ghist0   = hist4 + 4 * NNODES;
    int* ghist1   = ghist0 + 4 * NBINS;
    int* cnts     = ghist1 + 4 * NBINS;
    int* incl4    = (int*)alloc((size_t)4 * NNODES * 4);
    int* bsumb    = (int*)alloc(1024 * 4);
    int* rowp4    = (int*)alloc(((size_t)4 * NNODES + 1) * 4);
    int* cursor4  = (int*)alloc((size_t)4 * NNODES * 4);
    int2* sedge4  = (int2*)alloc((size_t)4 * NEDGES * 8);
    int*   gt_idx = (int*)alloc((size_t)4 * 128 * 4);
    float* gt_val = (float*)alloc((size_t)4 * 128 * 4);
    int*   eq_idx = (int*)alloc((size_t)4 * EQCAP * 4);
    float* eq_val = (float*)alloc((size_t)4 * EQCAP * 4);

    hipMemsetAsync(hist4, 0, ((size_t)4 * NNODES + 8 * NBINS + 64) * 4, stream);
    norm_kernel<<<1, 128, 0, stream>>>(l0p[9], l1p[9], norms);

    const int M4 = 4 * NNODES;
    const int NB4 = (M4 + 255) / 256;          // 782
    const int NB = (NNODES + 255) / 256;       // 196
    const int EB = (NEDGES + 255) / 256;       // 1563

    // ---- batched CSR build for all 4 timesteps ----
    hist4_kernel<<<dim3(EB, 4), 256, 0, stream>>>(edge_dst, hist4, NEDGES);
    scanA_kernel<<<NB4, 256, 0, stream>>>(hist4, incl4, bsumb, M4);
    scanB_kernel<<<1, 1024, 0, stream>>>(bsumb, NB4);
    scanC_kernel<<<NB4, 256, 0, stream>>>(hist4, incl4, bsumb, rowp4, cursor4, M4);
    bucket4_kernel<<<dim3(EB * 8, 4), 256, 0, stream>>>(edge_src, edge_dst, edge_weight, cursor4, sedge4, NEDGES);

    // ---- L0: scores + top-k + z for ALL t (input-only dependence) ----
    scores_hist4_kernel<<<dim3(NB, 4), 256, 0, stream>>>(node_embs, l0p[9], norms, mask, scores4, ghist0, NNODES);
    topk_collect_kernel<<<dim3(NB, 4), 256, 0, stream>>>(scores4, ghist0, cnts, gt_idx, gt_val, eq_idx, eq_val, NNODES, 128);
    topk_finish_kernel<128><<<4, 1024, 0, stream>>>(ghist0, cnts, gt_idx, gt_val, eq_idx, eq_val, node_embs, z0buf, NNODES);

    // ---- L0 GRU recurrence (all t, one kernel), then batched XW + sliced agg ----
    gru_multi_kernel<128><<<16, 256, 0, stream>>>(gcn_w0, z0buf,
        l0p[0], l0p[1], l0p[2], l0p[3], l0p[4], l0p[5], l0p[6], l0p[7], l0p[8], Q0n);
    xw_kernel<128, false><<<dim3((NNODES + 31) / 32, 4), 256, 0, stream>>>(node_embs, Q0n, XW0buf, NNODES);
    {
        const int dstBlocksS = (NNODES + 31) / 32;          // 1563 (NPB=32 for SW=32)
        const int gridS = ((dstBlocksS + 1) / 2) * 8;       // 6256
        for (int P = 0; P < 4; P++) {
            agg_slice_kernel<32, true><<<gridS, 256, 0, stream>>>(XW0buf, rowp4, sedge4, h1buf, NNODES, P,
                l1p[9], norms, mask, scores1, ghist1, scoreacc);
        }
    }

    // ---- L1: top-k for all t (h1+scores1 ready), GRU recurrence, batched XW + agg -> d_out ----
    topk_collect_kernel<<<dim3(NB, 4), 256, 0, stream>>>(scores1, ghist1, cnts, gt_idx, gt_val, eq_idx, eq_val, NNODES, 64);
    topk_finish_kernel<64><<<4, 1024, 0, stream>>>(ghist1, cnts, gt_idx, gt_val, eq_idx, eq_val, h1buf, z1buf, NNODES);
    gru_multi_kernel<64><<<8, 256, 0, stream>>>(gcn_w1, z1buf,
        l1p[0], l1p[1], l1p[2], l1p[3], l1p[4], l1p[5], l1p[6], l1p[7], l1p[8], Q1n);
    xw_kernel<64, true><<<dim3((NNODES + 63) / 64, 4), 256, 0, stream>>>(h1buf, Q1n, XW1buf, NNODES);
    {
        const int dstBlocks1 = (NNODES + 15) / 16;          // 3125 (NPB=16 for COLS=64)
        const int grid1 = ((dstBlocks1 + 1) / 2) * 8;       // 12504
        agg_kernel<64><<<grid1, 256, 0, stream>>>(XW1buf, rowp4, sedge4, (float*)d_out, NNODES);
    }
}

// Round 5
// 1150.497 us; speedup vs baseline: 1.1511x; 1.0350x over previous
//
#include <hip/hip_runtime.h>
#include <math.h>

#define T_STEPS 4
#define NNODES 50000
#define NEDGES 400000
#define FIN 128   // input feature dim for both layers
#define NBINS 8192
#define BINSHIFT 19  // 32-13
#define EQCAP 4096
#define DSHARD 6250  // NNODES/8

__device__ __forceinline__ float sigmoidf_(float x) { return 1.0f / (1.0f + __expf(-x)); }

__device__ __forceinline__ unsigned int key_of(float s) {
    unsigned int u = __float_as_uint(s);
    return (u & 0x80000000u) ? ~u : (u | 0x80000000u);
}

__device__ __forceinline__ unsigned short f2bf(float f) {
    unsigned int u = __float_as_uint(f);
    unsigned int r = (u + 0x7FFFu + ((u >> 16) & 1u)) >> 16;
    return (unsigned short)r;
}
__device__ __forceinline__ float bf2f(unsigned short h) {
    return __uint_as_float(((unsigned int)h) << 16);
}

typedef float f4v __attribute__((ext_vector_type(4)));
__device__ __forceinline__ void nt_store4(float* p, float4 v) {
    f4v w; w.x = v.x; w.y = v.y; w.z = v.z; w.w = v.w;
    __builtin_nontemporal_store(w, (f4v*)p);
}

// ---------------- norms of the two scorers ----------------
__global__ void norm_kernel(const float* __restrict__ s0, const float* __restrict__ s1,
                            float* __restrict__ norms) {
    __shared__ float red[128];
    int tid = threadIdx.x;  // 128 threads
    float a = s0[tid];
    red[tid] = a * a;
    __syncthreads();
    for (int off = 64; off > 0; off >>= 1) { if (tid < off) red[tid] += red[tid + off]; __syncthreads(); }
    if (tid == 0) norms[0] = sqrtf(red[0]);
    __syncthreads();
    float b = s1[tid];
    red[tid] = b * b;
    __syncthreads();
    for (int off = 64; off > 0; off >>= 1) { if (tid < off) red[tid] += red[tid + off]; __syncthreads(); }
    if (tid == 0) norms[1] = sqrtf(red[0]);
}

// ---------------- L0 scores for ALL t + topk histogram ----------------
// grid: (ceil(N/256), T_STEPS)
__global__ void scores_hist4_kernel(const float* __restrict__ node_embs, const float* __restrict__ scorer,
                                    const float* __restrict__ norms,
                                    const float* __restrict__ mask, float* __restrict__ scores4,
                                    int* __restrict__ ghist4, int N) {
    __shared__ float sc[FIN];
    if (threadIdx.x < FIN) sc[threadIdx.x] = scorer[threadIdx.x];
    __syncthreads();
    int t = blockIdx.y;
    int n = blockIdx.x * blockDim.x + threadIdx.x;
    if (n >= N) return;
    const float4* xr = (const float4*)(node_embs + ((size_t)t * N + n) * FIN);
    float acc = 0.f;
#pragma unroll 8
    for (int k4 = 0; k4 < FIN / 4; k4++) {
        float4 v = xr[k4];
        acc += v.x * sc[k4 * 4] + v.y * sc[k4 * 4 + 1] + v.z * sc[k4 * 4 + 2] + v.w * sc[k4 * 4 + 3];
    }
    float s = acc / norms[0] + mask[(size_t)t * N + n];
    scores4[(size_t)t * N + n] = s;
    atomicAdd(&ghist4[t * NBINS + (key_of(s) >> BINSHIFT)], 1);
}

// ---------------- parallel top-k collect: each block re-derives critical bin ----------------
// grid: (196, ntasks). task strides: scores N, ghist NBINS, cnts 2, gt 128, eq EQCAP
__global__ void __launch_bounds__(256)
topk_collect_kernel(const float* __restrict__ scores_b, const int* __restrict__ ghist_b,
                    int* __restrict__ cnts_b, int* __restrict__ gt_idx_b, float* __restrict__ gt_val_b,
                    int* __restrict__ eq_idx_b, float* __restrict__ eq_val_b, int N, int K) {
    __shared__ int h[NBINS];
    __shared__ int part[256];
    __shared__ int s_bin;
    int tid = threadIdx.x;
    int task = blockIdx.y;
    const int* gh = ghist_b + (size_t)task * NBINS;
    for (int i = tid; i < NBINS; i += 256) h[i] = gh[i];
    __syncthreads();
    int s = 0;
#pragma unroll
    for (int i = 0; i < NBINS / 256; i++) s += h[tid * (NBINS / 256) + i];
    part[tid] = s;
    __syncthreads();
    for (int off = 1; off < 256; off <<= 1) {
        int v = (tid + off < 256) ? part[tid + off] : 0;
        __syncthreads();
        part[tid] += v;
        __syncthreads();
    }
    {
        int run = (tid == 255) ? 0 : part[tid + 1];
        const int CH = NBINS / 256;
        for (int b = tid * CH + CH - 1; b >= tid * CH; b--) {
            int Sb = run + h[b];
            if (Sb >= K && run < K) s_bin = b;
            run = Sb;
        }
    }
    __syncthreads();
    int bin = s_bin;
    const float* scores = scores_b + (size_t)task * N;
    int* cg = cnts_b + task * 2;
    for (int n = blockIdx.x * 256 + tid; n < N; n += gridDim.x * 256) {
        float sc = scores[n];
        unsigned int key = key_of(sc);
        int kb = (int)(key >> BINSHIFT);
        if (kb > bin) {
            int p = atomicAdd(&cg[0], 1);
            gt_idx_b[task * 128 + p] = n; gt_val_b[task * 128 + p] = sc;
        } else if (kb == bin) {
            int p = atomicAdd(&cg[1], 1);
            if (p < EQCAP) { eq_idx_b[task * EQCAP + p] = n; eq_val_b[task * EQCAP + p] = sc; }
        }
    }
}

// ---------------- finish: exact rank + sort + z build; self-zero ghist & cnts ----------------
// grid: (ntasks). need = K - cnt_gt. z[r*K+j] = X[idx_j*FIN+r]*tanh(val_j)
template <int K>
__global__ void __launch_bounds__(1024)
topk_finish_kernel(int* __restrict__ ghist_b, int* __restrict__ cnts_b,
                   const int* __restrict__ gt_idx_b, const float* __restrict__ gt_val_b,
                   const int* __restrict__ eq_idx_b, const float* __restrict__ eq_val_b,
                   const float* __restrict__ X_b, float* __restrict__ z_b, int N) {
    __shared__ int sidx[K];
    __shared__ float sval[K];
    __shared__ unsigned int ek[EQCAP];
    __shared__ int ei[EQCAP];
    __shared__ int out_idx[K];
    __shared__ float out_tanh[K];
    int tid = threadIdx.x;
    int task = blockIdx.x;
    int* cg = cnts_b + task * 2;
    int g = cg[0];
    int m = min(cg[1], EQCAP);
    int need = K - g;
    const int* gt_idx = gt_idx_b + task * 128;
    const float* gt_val = gt_val_b + task * 128;
    const int* eq_idx = eq_idx_b + task * EQCAP;
    const float* eq_val = eq_val_b + task * EQCAP;
    const float* X = X_b + (size_t)task * N * FIN;
    float* z = z_b + (size_t)task * FIN * K;

    for (int i = tid; i < g; i += 1024) { sidx[i] = gt_idx[i]; sval[i] = gt_val[i]; }
    for (int i = tid; i < m; i += 1024) { ek[i] = key_of(eq_val[i]); ei[i] = eq_idx[i]; }
    __syncthreads();
    for (int i = tid; i < m; i += 1024) {
        int myi = ei[i];
        unsigned int myk = ek[i];
        int rank = 0;
        for (int j = 0; j < m; j++)
            rank += (ek[j] > myk) || (ek[j] == myk && ei[j] < myi);
        if (rank < need) { sidx[g + rank] = myi; sval[g + rank] = eq_val[i]; }
    }
    __syncthreads();
    if (tid < K) {
        float v = sval[tid];
        int id = sidx[tid];
        unsigned int myk = key_of(v);
        int rank = 0;
        for (int j = 0; j < K; j++) {
            unsigned int kj = key_of(sval[j]);
            rank += (kj > myk) || (kj == myk && sidx[j] < id);
        }
        out_idx[rank] = id;
        out_tanh[rank] = tanhf(v);
    }
    // self-zero for reuse (cnts slots shared between L0 and L1 passes)
    int* gh = ghist_b + (size_t)task * NBINS;
    for (int i = tid; i < NBINS; i += 1024) gh[i] = 0;
    if (tid == 0) { cg[0] = 0; cg[1] = 0; }
    __syncthreads();
    for (int i = tid; i < K * FIN; i += 1024) {
        int j = i >> 7;        // / FIN
        int r = i & 127;       // % FIN
        z[r * K + j] = X[(size_t)out_idx[j] * FIN + r] * out_tanh[j];
    }
}

// ---------------- multi-step fused GRU: all T steps in one kernel ----------------
// Column-separable recurrence: block owns 8 columns, holds Q in LDS across steps.
template <int COLS>
__global__ void __launch_bounds__(256)
gru_multi_kernel(const float* __restrict__ Qinit, const float* __restrict__ z_all,
                 const float* __restrict__ Wu, const float* __restrict__ Uu, const float* __restrict__ Bu,
                 const float* __restrict__ Wr, const float* __restrict__ Ur, const float* __restrict__ Br,
                 const float* __restrict__ Wh, const float* __restrict__ Uh, const float* __restrict__ Bh,
                 float* __restrict__ Qn_all) {
    __shared__ float zc[128][8];
    __shared__ float qc[128][8];
    __shared__ float rq[128][8];
    __shared__ float ul[128][8];
    int tid = threadIdx.x;
    int c0 = blockIdx.x * 8;
    for (int i = tid; i < 1024; i += 256) {
        int r = i >> 3, c = i & 7;
        qc[r][c] = Qinit[r * COLS + c0 + c];
    }
    for (int t = 0; t < T_STEPS; t++) {
        __syncthreads();   // protect zc (prev step readers) + publish qc updates
        const float* z = z_all + (size_t)t * 128 * COLS;
        for (int i = tid; i < 1024; i += 256) {
            int r = i >> 3, c = i & 7;
            zc[r][c] = z[r * COLS + c0 + c];
        }
        __syncthreads();
#pragma unroll
        for (int e = 0; e < 4; e++) {
            int idx = tid + 256 * e;
            int r = idx >> 3, c = idx & 7;
            float au = Bu[r * COLS + c0 + c], ar = Br[r * COLS + c0 + c];
            for (int k = 0; k < 128; k++) {
                float zz = zc[k][c], qq = qc[k][c];
                au += Wu[r * 128 + k] * zz + Uu[r * 128 + k] * qq;
                ar += Wr[r * 128 + k] * zz + Ur[r * 128 + k] * qq;
            }
            ul[r][c] = sigmoidf_(au);
            rq[r][c] = sigmoidf_(ar) * qc[r][c];
        }
        __syncthreads();
        float* Qn = Qn_all + (size_t)t * 128 * COLS;
#pragma unroll
        for (int e = 0; e < 4; e++) {
            int idx = tid + 256 * e;
            int r = idx >> 3, c = idx & 7;
            float s = Bh[r * COLS + c0 + c];
            for (int k = 0; k < 128; k++) {
                s += Wh[r * 128 + k] * zc[k][c] + Uh[r * 128 + k] * rq[k][c];
            }
            float h = tanhf(s);
            float u = ul[r][c];
            float qn = (1.f - u) * qc[r][c] + u * h;
            Qn[r * COLS + c0 + c] = qn;
            qc[r][c] = qn;     // own element only; published at next loop-top barrier
        }
    }
}

// ---------------- XW(t) = X(t) @ Qn(t), 64-col slices for occupancy ----------------
// grid: (ceil(N/64), T_STEPS, ostride/64). Each block stages a 128x64 Q-slice (32KB LDS
// -> 5 blocks/CU vs 2 at 64KB) and computes 64 rows x 64 cols. Output values bitwise
// identical to the unsliced kernel (same k-order per element; columns partitioned).
template <bool BF16>
__global__ void __launch_bounds__(256)
xw_kernel(const float* __restrict__ X_b, const float* __restrict__ Qn_all,
          void* __restrict__ outp, int N, int ostride) {
    constexpr int SW = 64;          // slice width (cols)
    constexpr int TPR = SW / 4;     // 16 threads per row
    constexpr int RPG = 256 / TPR;  // 16 rows per group
    constexpr int RPB = RPG * 4;    // 64 rows per block
    int t = blockIdx.y;
    int coff = blockIdx.z * SW;
    const float* X = X_b + (size_t)t * N * FIN;
    const float* Qn = Qn_all + (size_t)t * 128 * ostride;
    __shared__ float4 qs[128 * TPR];   // 32 KB
    for (int i = threadIdx.x; i < 128 * TPR; i += 256) {
        int r = i / TPR, c4 = i % TPR;
        qs[i] = *(const float4*)(Qn + (size_t)r * ostride + coff + c4 * 4);
    }
    __syncthreads();
    int lane_c = threadIdx.x % TPR;
    int rloc = threadIdx.x / TPR;
    int base = blockIdx.x * RPB;
    int rows[4];
    float4 acc[4];
#pragma unroll
    for (int j = 0; j < 4; j++) {
        rows[j] = base + rloc + j * RPG;
        acc[j] = make_float4(0.f, 0.f, 0.f, 0.f);
    }
    int nc[4];
#pragma unroll
    for (int j = 0; j < 4; j++) nc[j] = min(rows[j], N - 1);

    for (int k4 = 0; k4 < 32; k4++) {
        float4 q0 = qs[(k4 * 4 + 0) * TPR + lane_c];
        float4 q1 = qs[(k4 * 4 + 1) * TPR + lane_c];
        float4 q2 = qs[(k4 * 4 + 2) * TPR + lane_c];
        float4 q3 = qs[(k4 * 4 + 3) * TPR + lane_c];
#pragma unroll
        for (int j = 0; j < 4; j++) {
            float4 xv = ((const float4*)(X + (size_t)nc[j] * FIN))[k4];
            acc[j].x += xv.x * q0.x + xv.y * q1.x + xv.z * q2.x + xv.w * q3.x;
            acc[j].y += xv.x * q0.y + xv.y * q1.y + xv.z * q2.y + xv.w * q3.y;
            acc[j].z += xv.x * q0.z + xv.y * q1.z + xv.z * q2.z + xv.w * q3.z;
            acc[j].w += xv.x * q0.w + xv.y * q1.w + xv.z * q2.w + xv.w * q3.w;
        }
    }
#pragma unroll
    for (int j = 0; j < 4; j++) {
        if (rows[j] < N) {
            if (BF16) {
                ushort4 o;
                o.x = f2bf(acc[j].x); o.y = f2bf(acc[j].y);
                o.z = f2bf(acc[j].z); o.w = f2bf(acc[j].w);
                ((ushort4*)((unsigned short*)outp + ((size_t)t * N + rows[j]) * ostride + coff))[lane_c] = o;
            } else {
                ((float4*)((float*)outp + ((size_t)t * N + rows[j]) * ostride + coff))[lane_c] = acc[j];
            }
        }
    }
}

// ---------------- batched CSR build over all 4 timesteps (sorted by (t,dst)) ----------------
__global__ void hist4_kernel(const int* __restrict__ dst, int* __restrict__ hist4, int E) {
    int e = blockIdx.x * blockDim.x + threadIdx.x;
    if (e >= E) return;
    int t = blockIdx.y;
    atomicAdd(&hist4[t * NNODES + dst[(size_t)t * E + e]], 1);
}

__global__ void __launch_bounds__(256)
scanA_kernel(const int* __restrict__ hist, int* __restrict__ incl, int* __restrict__ bsum, int M) {
    __shared__ int sh[256];
    int gid = blockIdx.x * 256 + threadIdx.x;
    int v = (gid < M) ? hist[gid] : 0;
    sh[threadIdx.x] = v;
    __syncthreads();
    for (int off = 1; off < 256; off <<= 1) {
        int u = (threadIdx.x >= off) ? sh[threadIdx.x - off] : 0;
        __syncthreads();
        sh[threadIdx.x] += u;
        __syncthreads();
    }
    if (gid < M) incl[gid] = sh[threadIdx.x];
    if (threadIdx.x == 255) bsum[blockIdx.x] = sh[255];
}

__global__ void __launch_bounds__(1024)
scanB_kernel(int* __restrict__ bsum, int nb) {
    __shared__ int sh[1024];
    int tid = threadIdx.x;
    int v = (tid < nb) ? bsum[tid] : 0;
    sh[tid] = v;
    __syncthreads();
    for (int off = 1; off < 1024; off <<= 1) {
        int u = (tid >= off) ? sh[tid - off] : 0;
        __syncthreads();
        sh[tid] += u;
        __syncthreads();
    }
    if (tid < nb) bsum[tid] = (tid == 0) ? 0 : sh[tid - 1];
}

__global__ void __launch_bounds__(256)
scanC_kernel(const int* __restrict__ hist, const int* __restrict__ incl,
             const int* __restrict__ bsum, int* __restrict__ row_ptr,
             int* __restrict__ cursor, int M) {
    int gid = blockIdx.x * 256 + threadIdx.x;
    if (gid < M) {
        int inc = incl[gid] + bsum[gid / 256];
        int ex = inc - hist[gid];
        row_ptr[gid] = ex;
        cursor[gid] = ex;
        if (gid == M - 1) row_ptr[M] = inc;
    }
}

// dst-range-sharded scatter (R7 win: keeps sedge writes XCD-local, lines coalesce)
__global__ void bucket4_kernel(const int* __restrict__ src, const int* __restrict__ dst,
                               const float* __restrict__ w, int* __restrict__ cursor,
                               int2* __restrict__ sedge, int E) {
    int bx = blockIdx.x;
    int shard = bx & 7;
    int e = (bx >> 3) * 256 + threadIdx.x;
    if (e >= E) return;
    int t = blockIdx.y;
    size_t ge = (size_t)t * E + e;
    int d = dst[ge];
    if (d / DSHARD != shard) return;
    int pos = atomicAdd(&cursor[t * NNODES + d], 1);
    int2 pk;
    pk.x = src[ge];
    pk.y = __float_as_int(w[ge]);
    sedge[pos] = pk;
}

// ---------------- L0 CSR aggregation, column-sliced: one launch per 32-col slice ----------------
// Each launch gathers exactly 1 cache line (128B) per edge from a 25.6MB chip-wide slice
// (6.4MB per t) -> L3-resident across the pass; launch boundary enforces phase alignment.
// Summation order per output element identical to the unsliced kernel (edge order unchanged).
// Scores accumulate across passes in scoreacc (one owner thread per (t,node) per pass).
template <int SW, bool SCORE>
__global__ void __launch_bounds__(256)
agg_slice_kernel(const float* __restrict__ XW_b, const int* __restrict__ row_ptr4,
                 const int2* __restrict__ sedge,
                 float* __restrict__ out_b, int N, int P,
                 const float* __restrict__ scorer, const float* __restrict__ norms,
                 const float* __restrict__ mask_b, float* __restrict__ scores_b,
                 int* __restrict__ ghist_b, float* __restrict__ scoreacc) {
    constexpr int TPN = SW / 4;        // 8 threads per node
    constexpr int NPB = 256 / TPN;     // 32 nodes per block
    constexpr int NPASS = FIN / SW;    // 4
    int lin = blockIdx.x;
    int xcd = lin & 7;
    int slot = lin >> 3;
    int t = xcd >> 1;                 // XCDs {0,1}->t0, {2,3}->t1, ...
    int db = slot * 2 + (xcd & 1);
    int dstBlocks = (N + NPB - 1) / NPB;
    if (db >= dstBlocks) return;
    int node = db * NPB + threadIdx.x / TPN;
    if (node >= N) return;
    int lane = threadIdx.x % TPN;
    const int* rp = row_ptr4 + (size_t)t * N;
    int beg = rp[node], end = rp[node + 1];
    const float* XW = XW_b + (size_t)t * N * FIN + P * SW;
    float4 a0 = make_float4(0.f, 0.f, 0.f, 0.f);
    float4 a1 = a0, a2 = a0, a3 = a0;
    int i = beg;
    for (; i + 4 <= end; i += 4) {
        int2 p0 = sedge[i], p1 = sedge[i + 1], p2 = sedge[i + 2], p3 = sedge[i + 3];
        float4 v0 = ((const float4*)(XW + (size_t)p0.x * FIN))[lane];
        float4 v1 = ((const float4*)(XW + (size_t)p1.x * FIN))[lane];
        float4 v2 = ((const float4*)(XW + (size_t)p2.x * FIN))[lane];
        float4 v3 = ((const float4*)(XW + (size_t)p3.x * FIN))[lane];
        float w0 = __int_as_float(p0.y), w1 = __int_as_float(p1.y);
        float w2 = __int_as_float(p2.y), w3 = __int_as_float(p3.y);
        a0.x += v0.x * w0; a0.y += v0.y * w0; a0.z += v0.z * w0; a0.w += v0.w * w0;
        a1.x += v1.x * w1; a1.y += v1.y * w1; a1.z += v1.z * w1; a1.w += v1.w * w1;
        a2.x += v2.x * w2; a2.y += v2.y * w2; a2.z += v2.z * w2; a2.w += v2.w * w2;
        a3.x += v3.x * w3; a3.y += v3.y * w3; a3.z += v3.z * w3; a3.w += v3.w * w3;
    }
    for (; i < end; i++) {
        int2 pk = sedge[i];
        float wt = __int_as_float(pk.y);
        float4 v = ((const float4*)(XW + (size_t)pk.x * FIN))[lane];
        a0.x += v.x * wt; a0.y += v.y * wt; a0.z += v.z * wt; a0.w += v.w * wt;
    }
    float4 acc;
    acc.x = (a0.x + a1.x) + (a2.x + a3.x);
    acc.y = (a0.y + a1.y) + (a2.y + a3.y);
    acc.z = (a0.z + a1.z) + (a2.z + a3.z);
    acc.w = (a0.w + a1.w) + (a2.w + a3.w);
    acc.x = fmaxf(acc.x, 0.f); acc.y = fmaxf(acc.y, 0.f);
    acc.z = fmaxf(acc.z, 0.f); acc.w = fmaxf(acc.w, 0.f);
    nt_store4(out_b + ((size_t)t * N + node) * FIN + P * SW + lane * 4, acc);
    if (SCORE) {
        float4 sc4 = ((const float4*)(scorer + P * SW))[lane];
        float partial = acc.x * sc4.x + acc.y * sc4.y + acc.z * sc4.z + acc.w * sc4.w;
#pragma unroll
        for (int off = TPN / 2; off > 0; off >>= 1) partial += __shfl_xor(partial, off, TPN);
        if (lane == 0) {
            float* sa = scoreacc + (size_t)t * N + node;
            float tot = (P == 0 ? 0.f : *sa) + partial;
            if (P == NPASS - 1) {
                float s = tot / norms[1] + mask_b[(size_t)t * N + node];
                scores_b[(size_t)t * N + node] = s;
                atomicAdd(&ghist_b[t * NBINS + (key_of(s) >> BINSHIFT)], 1);
            } else {
                *sa = tot;
            }
        }
    }
}

// ---------------- L1 CSR aggregation (bf16 gather, fp32 out) ----------------
// 1D grid; xcd = blockIdx&7 picks t (2 XCDs per t); per-t bf16 XW1 = 6.4MB.
template <int COLS>
__global__ void __launch_bounds__(256)
agg_kernel(const unsigned short* __restrict__ XWb, const int* __restrict__ row_ptr4,
           const int2* __restrict__ sedge,
           float* __restrict__ out_b, int N) {
    constexpr int TPN = COLS / 4;
    constexpr int NPB = 256 / TPN;
    int lin = blockIdx.x;
    int xcd = lin & 7;
    int slot = lin >> 3;
    int t = xcd >> 1;
    int db = slot * 2 + (xcd & 1);
    int dstBlocks = (N + NPB - 1) / NPB;
    if (db >= dstBlocks) return;
    int node = db * NPB + threadIdx.x / TPN;
    if (node >= N) return;
    int lane = threadIdx.x % TPN;
    const int* rp = row_ptr4 + (size_t)t * N;
    int beg = rp[node], end = rp[node + 1];
    const unsigned short* XW = XWb + (size_t)t * N * COLS;
    float4 a0 = make_float4(0.f, 0.f, 0.f, 0.f);
    float4 a1 = a0, a2 = a0, a3 = a0;
    int i = beg;
    for (; i + 4 <= end; i += 4) {
        int2 p0 = sedge[i], p1 = sedge[i + 1], p2 = sedge[i + 2], p3 = sedge[i + 3];
        ushort4 v0 = ((const ushort4*)(XW + (size_t)p0.x * COLS))[lane];
        ushort4 v1 = ((const ushort4*)(XW + (size_t)p1.x * COLS))[lane];
        ushort4 v2 = ((const ushort4*)(XW + (size_t)p2.x * COLS))[lane];
        ushort4 v3 = ((const ushort4*)(XW + (size_t)p3.x * COLS))[lane];
        float w0 = __int_as_float(p0.y), w1 = __int_as_float(p1.y);
        float w2 = __int_as_float(p2.y), w3 = __int_as_float(p3.y);
        a0.x += bf2f(v0.x) * w0; a0.y += bf2f(v0.y) * w0; a0.z += bf2f(v0.z) * w0; a0.w += bf2f(v0.w) * w0;
        a1.x += bf2f(v1.x) * w1; a1.y += bf2f(v1.y) * w1; a1.z += bf2f(v1.z) * w1; a1.w += bf2f(v1.w) * w1;
        a2.x += bf2f(v2.x) * w2; a2.y += bf2f(v2.y) * w2; a2.z += bf2f(v2.z) * w2; a2.w += bf2f(v2.w) * w2;
        a3.x += bf2f(v3.x) * w3; a3.y += bf2f(v3.y) * w3; a3.z += bf2f(v3.z) * w3; a3.w += bf2f(v3.w) * w3;
    }
    for (; i < end; i++) {
        int2 pk = sedge[i];
        float wt = __int_as_float(pk.y);
        ushort4 v = ((const ushort4*)(XW + (size_t)pk.x * COLS))[lane];
        a0.x += bf2f(v.x) * wt; a0.y += bf2f(v.y) * wt;
        a0.z += bf2f(v.z) * wt; a0.w += bf2f(v.w) * wt;
    }
    float4 acc;
    acc.x = (a0.x + a1.x) + (a2.x + a3.x);
    acc.y = (a0.y + a1.y) + (a2.y + a3.y);
    acc.z = (a0.z + a1.z) + (a2.z + a3.z);
    acc.w = (a0.w + a1.w) + (a2.w + a3.w);
    acc.x = fmaxf(acc.x, 0.f); acc.y = fmaxf(acc.y, 0.f);
    acc.z = fmaxf(acc.z, 0.f); acc.w = fmaxf(acc.w, 0.f);
    nt_store4(out_b + ((size_t)t * N + node) * COLS + lane * 4, acc);
}

extern "C" void kernel_launch(void* const* d_in, const int* in_sizes, int n_in,
                              void* d_out, int out_size, void* d_ws, size_t ws_size,
                              hipStream_t stream) {
    const float* node_embs   = (const float*)d_in[0];
    const float* mask        = (const float*)d_in[1];
    const int*   edge_src    = (const int*)d_in[2];
    const int*   edge_dst    = (const int*)d_in[3];
    const float* edge_weight = (const float*)d_in[4];
    const float* gcn_w0      = (const float*)d_in[5];
    const float* gcn_w1      = (const float*)d_in[6];
    const float* l0p[10];
    const float* l1p[10];
    for (int i = 0; i < 10; i++) l0p[i] = (const float*)d_in[7 + i];
    for (int i = 0; i < 10; i++) l1p[i] = (const float*)d_in[17 + i];
    // l*p: 0=Wu 1=Uu 2=Bu 3=Wr 4=Ur 5=Br 6=Wh 7=Uh 8=Bh 9=scorer

    char* ws = (char*)d_ws;
    size_t off = 0;
    auto alloc = [&](size_t bytes) -> void* {
        void* p = ws + off;
        off += (bytes + 255) / 256 * 256;
        return p;
    };
    float* XW0buf = (float*)alloc((size_t)4 * NNODES * 128 * 4);          // fp32, all t (102 MB)
    float* h1buf  = (float*)alloc((size_t)4 * NNODES * 128 * 4);          // fp32, all t (102 MB)
    unsigned short* XW1buf = (unsigned short*)alloc((size_t)4 * NNODES * 64 * 2);  // bf16, all t
    float* scores4= (float*)alloc((size_t)4 * NNODES * 4);                // L0 scores (all t)
    float* scores1= (float*)alloc((size_t)4 * NNODES * 4);                // L1 scores (all t)
    float* scoreacc=(float*)alloc((size_t)4 * NNODES * 4);                // partial L1 score dots
    float* z0buf  = (float*)alloc((size_t)4 * 128 * 128 * 4);
    float* z1buf  = (float*)alloc((size_t)4 * 128 * 64 * 4);
    float* Q0n    = (float*)alloc((size_t)4 * 128 * 128 * 4);
    float* Q1n    = (float*)alloc((size_t)4 * 128 * 64 * 4);
    float* norms  = (float*)alloc(64);
    // combined zeroed region: hist4[4N] + ghist0[4*NBINS] + ghist1[4*NBINS] + cnts[64]
    int* hist4    = (int*)alloc(((size_t)4 * NNODES + 8 * NBINS + 64) * 4);
    int* ghist0   = hist4 + 4 * NNODES;
    int* ghist1   = ghist0 + 4 * NBINS;
    int* cnts     = ghist1 + 4 * NBINS;
    int* incl4    = (int*)alloc((size_t)4 * NNODES * 4);
    int* bsumb    = (int*)alloc(1024 * 4);
    int* rowp4    = (int*)alloc(((size_t)4 * NNODES + 1) * 4);
    int* cursor4  = (int*)alloc((size_t)4 * NNODES * 4);
    int2* sedge4  = (int2*)alloc((size_t)4 * NEDGES * 8);
    int*   gt_idx = (int*)alloc((size_t)4 * 128 * 4);
    float* gt_val = (float*)alloc((size_t)4 * 128 * 4);
    int*   eq_idx = (int*)alloc((size_t)4 * EQCAP * 4);
    float* eq_val = (float*)alloc((size_t)4 * EQCAP * 4);

    hipMemsetAsync(hist4, 0, ((size_t)4 * NNODES + 8 * NBINS + 64) * 4, stream);
    norm_kernel<<<1, 128, 0, stream>>>(l0p[9], l1p[9], norms);

    const int M4 = 4 * NNODES;
    const int NB4 = (M4 + 255) / 256;          // 782
    const int NB = (NNODES + 255) / 256;       // 196
    const int EB = (NEDGES + 255) / 256;       // 1563

    // ---- batched CSR build for all 4 timesteps ----
    hist4_kernel<<<dim3(EB, 4), 256, 0, stream>>>(edge_dst, hist4, NEDGES);
    scanA_kernel<<<NB4, 256, 0, stream>>>(hist4, incl4, bsumb, M4);
    scanB_kernel<<<1, 1024, 0, stream>>>(bsumb, NB4);
    scanC_kernel<<<NB4, 256, 0, stream>>>(hist4, incl4, bsumb, rowp4, cursor4, M4);
    bucket4_kernel<<<dim3(EB * 8, 4), 256, 0, stream>>>(edge_src, edge_dst, edge_weight, cursor4, sedge4, NEDGES);

    // ---- L0: scores + top-k + z for ALL t (input-only dependence) ----
    scores_hist4_kernel<<<dim3(NB, 4), 256, 0, stream>>>(node_embs, l0p[9], norms, mask, scores4, ghist0, NNODES);
    topk_collect_kernel<<<dim3(NB, 4), 256, 0, stream>>>(scores4, ghist0, cnts, gt_idx, gt_val, eq_idx, eq_val, NNODES, 128);
    topk_finish_kernel<128><<<4, 1024, 0, stream>>>(ghist0, cnts, gt_idx, gt_val, eq_idx, eq_val, node_embs, z0buf, NNODES);

    // ---- L0 GRU recurrence (all t, one kernel), then batched XW + sliced agg ----
    gru_multi_kernel<128><<<16, 256, 0, stream>>>(gcn_w0, z0buf,
        l0p[0], l0p[1], l0p[2], l0p[3], l0p[4], l0p[5], l0p[6], l0p[7], l0p[8], Q0n);
    {
        const int RB = (NNODES + 63) / 64;                  // 782
        xw_kernel<false><<<dim3(RB, 4, 2), 256, 0, stream>>>(node_embs, Q0n, XW0buf, NNODES, 128);
    }
    {
        const int dstBlocksS = (NNODES + 31) / 32;          // 1563 (NPB=32 for SW=32)
        const int gridS = ((dstBlocksS + 1) / 2) * 8;       // 6256
        for (int P = 0; P < 4; P++) {
            agg_slice_kernel<32, true><<<gridS, 256, 0, stream>>>(XW0buf, rowp4, sedge4, h1buf, NNODES, P,
                l1p[9], norms, mask, scores1, ghist1, scoreacc);
        }
    }

    // ---- L1: top-k for all t (h1+scores1 ready), GRU recurrence, batched XW + agg -> d_out ----
    topk_collect_kernel<<<dim3(NB, 4), 256, 0, stream>>>(scores1, ghist1, cnts, gt_idx, gt_val, eq_idx, eq_val, NNODES, 64);
    topk_finish_kernel<64><<<4, 1024, 0, stream>>>(ghist1, cnts, gt_idx, gt_val, eq_idx, eq_val, h1buf, z1buf, NNODES);
    gru_multi_kernel<64><<<8, 256, 0, stream>>>(gcn_w1, z1buf,
        l1p[0], l1p[1], l1p[2], l1p[3], l1p[4], l1p[5], l1p[6], l1p[7], l1p[8], Q1n);
    {
        const int RB = (NNODES + 63) / 64;                  // 782
        xw_kernel<true><<<dim3(RB, 4, 1), 256, 0, stream>>>(h1buf, Q1n, XW1buf, NNODES, 64);
    }
    {
        const int dstBlocks1 = (NNODES + 15) / 16;          // 3125 (NPB=16 for COLS=64)
        const int grid1 = ((dstBlocks1 + 1) / 2) * 8;       // 12504
        agg_kernel<64><<<grid1, 256, 0, stream>>>(XW1buf, rowp4, sedge4, (float*)d_out, NNODES);
    }
}

// Round 7
// 1004.779 us; speedup vs baseline: 1.3180x; 1.1450x over previous
//
#include <hip/hip_runtime.h>
#include <math.h>

#define T_STEPS 4
#define NNODES 50000
#define NEDGES 400000
#define FIN 128   // input feature dim for both layers
#define NBINS 8192
#define BINSHIFT 19  // 32-13
#define EQCAP 4096
#define DSHARD 6250  // NNODES/8

__device__ __forceinline__ float sigmoidf_(float x) { return 1.0f / (1.0f + __expf(-x)); }

__device__ __forceinline__ unsigned int key_of(float s) {
    unsigned int u = __float_as_uint(s);
    return (u & 0x80000000u) ? ~u : (u | 0x80000000u);
}

__device__ __forceinline__ unsigned short f2bf(float f) {
    unsigned int u = __float_as_uint(f);
    unsigned int r = (u + 0x7FFFu + ((u >> 16) & 1u)) >> 16;
    return (unsigned short)r;
}
__device__ __forceinline__ float bf2f(unsigned short h) {
    return __uint_as_float(((unsigned int)h) << 16);
}

typedef float f4v __attribute__((ext_vector_type(4)));
__device__ __forceinline__ void nt_store4(float* p, float4 v) {
    f4v w; w.x = v.x; w.y = v.y; w.z = v.z; w.w = v.w;
    __builtin_nontemporal_store(w, (f4v*)p);
}

// ---------------- norms of the two scorers ----------------
__global__ void norm_kernel(const float* __restrict__ s0, const float* __restrict__ s1,
                            float* __restrict__ norms) {
    __shared__ float red[128];
    int tid = threadIdx.x;  // 128 threads
    float a = s0[tid];
    red[tid] = a * a;
    __syncthreads();
    for (int off = 64; off > 0; off >>= 1) { if (tid < off) red[tid] += red[tid + off]; __syncthreads(); }
    if (tid == 0) norms[0] = sqrtf(red[0]);
    __syncthreads();
    float b = s1[tid];
    red[tid] = b * b;
    __syncthreads();
    for (int off = 64; off > 0; off >>= 1) { if (tid < off) red[tid] += red[tid + off]; __syncthreads(); }
    if (tid == 0) norms[1] = sqrtf(red[0]);
}

// ---------------- L0 scores for ALL t + topk histogram ----------------
// grid: (ceil(N/256), T_STEPS)
__global__ void scores_hist4_kernel(const float* __restrict__ node_embs, const float* __restrict__ scorer,
                                    const float* __restrict__ norms,
                                    const float* __restrict__ mask, float* __restrict__ scores4,
                                    int* __restrict__ ghist4, int N) {
    __shared__ float sc[FIN];
    if (threadIdx.x < FIN) sc[threadIdx.x] = scorer[threadIdx.x];
    __syncthreads();
    int t = blockIdx.y;
    int n = blockIdx.x * blockDim.x + threadIdx.x;
    if (n >= N) return;
    const float4* xr = (const float4*)(node_embs + ((size_t)t * N + n) * FIN);
    float acc = 0.f;
#pragma unroll 8
    for (int k4 = 0; k4 < FIN / 4; k4++) {
        float4 v = xr[k4];
        acc += v.x * sc[k4 * 4] + v.y * sc[k4 * 4 + 1] + v.z * sc[k4 * 4 + 2] + v.w * sc[k4 * 4 + 3];
    }
    float s = acc / norms[0] + mask[(size_t)t * N + n];
    scores4[(size_t)t * N + n] = s;
    atomicAdd(&ghist4[t * NBINS + (key_of(s) >> BINSHIFT)], 1);
}

// ---------------- parallel top-k collect: each block re-derives critical bin ----------------
// grid: (196, ntasks). task strides: scores N, ghist NBINS, cnts 2, gt 128, eq EQCAP
__global__ void __launch_bounds__(256)
topk_collect_kernel(const float* __restrict__ scores_b, const int* __restrict__ ghist_b,
                    int* __restrict__ cnts_b, int* __restrict__ gt_idx_b, float* __restrict__ gt_val_b,
                    int* __restrict__ eq_idx_b, float* __restrict__ eq_val_b, int N, int K) {
    __shared__ int h[NBINS];
    __shared__ int part[256];
    __shared__ int s_bin;
    int tid = threadIdx.x;
    int task = blockIdx.y;
    const int* gh = ghist_b + (size_t)task * NBINS;
    for (int i = tid; i < NBINS; i += 256) h[i] = gh[i];
    __syncthreads();
    int s = 0;
#pragma unroll
    for (int i = 0; i < NBINS / 256; i++) s += h[tid * (NBINS / 256) + i];
    part[tid] = s;
    __syncthreads();
    for (int off = 1; off < 256; off <<= 1) {
        int v = (tid + off < 256) ? part[tid + off] : 0;
        __syncthreads();
        part[tid] += v;
        __syncthreads();
    }
    {
        int run = (tid == 255) ? 0 : part[tid + 1];
        const int CH = NBINS / 256;
        for (int b = tid * CH + CH - 1; b >= tid * CH; b--) {
            int Sb = run + h[b];
            if (Sb >= K && run < K) s_bin = b;
            run = Sb;
        }
    }
    __syncthreads();
    int bin = s_bin;
    const float* scores = scores_b + (size_t)task * N;
    int* cg = cnts_b + task * 2;
    for (int n = blockIdx.x * 256 + tid; n < N; n += gridDim.x * 256) {
        float sc = scores[n];
        unsigned int key = key_of(sc);
        int kb = (int)(key >> BINSHIFT);
        if (kb > bin) {
            int p = atomicAdd(&cg[0], 1);
            gt_idx_b[task * 128 + p] = n; gt_val_b[task * 128 + p] = sc;
        } else if (kb == bin) {
            int p = atomicAdd(&cg[1], 1);
            if (p < EQCAP) { eq_idx_b[task * EQCAP + p] = n; eq_val_b[task * EQCAP + p] = sc; }
        }
    }
}

// ---------------- finish: exact rank + sort + z build; self-zero ghist & cnts ----------------
// grid: (ntasks). need = K - cnt_gt. z[r*K+j] = X[idx_j*FIN+r]*tanh(val_j)
template <int K>
__global__ void __launch_bounds__(1024)
topk_finish_kernel(int* __restrict__ ghist_b, int* __restrict__ cnts_b,
                   const int* __restrict__ gt_idx_b, const float* __restrict__ gt_val_b,
                   const int* __restrict__ eq_idx_b, const float* __restrict__ eq_val_b,
                   const float* __restrict__ X_b, float* __restrict__ z_b, int N) {
    __shared__ int sidx[K];
    __shared__ float sval[K];
    __shared__ unsigned int ek[EQCAP];
    __shared__ int ei[EQCAP];
    __shared__ int out_idx[K];
    __shared__ float out_tanh[K];
    int tid = threadIdx.x;
    int task = blockIdx.x;
    int* cg = cnts_b + task * 2;
    int g = cg[0];
    int m = min(cg[1], EQCAP);
    int need = K - g;
    const int* gt_idx = gt_idx_b + task * 128;
    const float* gt_val = gt_val_b + task * 128;
    const int* eq_idx = eq_idx_b + task * EQCAP;
    const float* eq_val = eq_val_b + task * EQCAP;
    const float* X = X_b + (size_t)task * N * FIN;
    float* z = z_b + (size_t)task * FIN * K;

    for (int i = tid; i < g; i += 1024) { sidx[i] = gt_idx[i]; sval[i] = gt_val[i]; }
    for (int i = tid; i < m; i += 1024) { ek[i] = key_of(eq_val[i]); ei[i] = eq_idx[i]; }
    __syncthreads();
    for (int i = tid; i < m; i += 1024) {
        int myi = ei[i];
        unsigned int myk = ek[i];
        int rank = 0;
        for (int j = 0; j < m; j++)
            rank += (ek[j] > myk) || (ek[j] == myk && ei[j] < myi);
        if (rank < need) { sidx[g + rank] = myi; sval[g + rank] = eq_val[i]; }
    }
    __syncthreads();
    if (tid < K) {
        float v = sval[tid];
        int id = sidx[tid];
        unsigned int myk = key_of(v);
        int rank = 0;
        for (int j = 0; j < K; j++) {
            unsigned int kj = key_of(sval[j]);
            rank += (kj > myk) || (kj == myk && sidx[j] < id);
        }
        out_idx[rank] = id;
        out_tanh[rank] = tanhf(v);
    }
    // self-zero for reuse (cnts slots shared between L0 and L1 passes)
    int* gh = ghist_b + (size_t)task * NBINS;
    for (int i = tid; i < NBINS; i += 1024) gh[i] = 0;
    if (tid == 0) { cg[0] = 0; cg[1] = 0; }
    __syncthreads();
    for (int i = tid; i < K * FIN; i += 1024) {
        int j = i >> 7;        // / FIN
        int r = i & 127;       // % FIN
        z[r * K + j] = X[(size_t)out_idx[j] * FIN + r] * out_tanh[j];
    }
}

// ---------------- multi-step fused GRU: one COLUMN per block ----------------
// grid: COLS blocks (128 L0, 64 L1), 256 threads. Phase1: thread = (row, gate u/r),
// float4 weight-row loads with dual accumulators. Phase2: tid<128 = candidate-gate row.
// 8x more blocks than the 8-col version and 4x less work per thread -> latency hidden.
template <int COLS>
__global__ void __launch_bounds__(256)
gru_multi_kernel(const float* __restrict__ Qinit, const float* __restrict__ z_all,
                 const float* __restrict__ Wu, const float* __restrict__ Uu, const float* __restrict__ Bu,
                 const float* __restrict__ Wr, const float* __restrict__ Ur, const float* __restrict__ Br,
                 const float* __restrict__ Wh, const float* __restrict__ Uh, const float* __restrict__ Bh,
                 float* __restrict__ Qn_all) {
    __shared__ float zc[128];
    __shared__ float qc[128];
    __shared__ float rq[128];
    __shared__ float ul[128];
    int tid = threadIdx.x;
    int c = blockIdx.x;
    int r = tid & 127;
    int gate = tid >> 7;
    if (tid < 128) qc[tid] = Qinit[tid * COLS + c];
    for (int t = 0; t < T_STEPS; t++) {
        __syncthreads();   // publish qc from prev step / protect zc
        const float* z = z_all + (size_t)t * 128 * COLS;
        if (tid < 128) zc[tid] = z[tid * COLS + c];
        __syncthreads();
        // phase 1: gate==0 -> update gate (ul), gate==1 -> reset gate (rq)
        {
            const float* W = gate ? Wr : Wu;
            const float* U = gate ? Ur : Uu;
            const float* B = gate ? Br : Bu;
            const float4* W4 = (const float4*)(W + r * 128);
            const float4* U4 = (const float4*)(U + r * 128);
            const float4* z4 = (const float4*)zc;
            const float4* q4 = (const float4*)qc;
            float aw = 0.f, au = 0.f;
#pragma unroll 8
            for (int k4 = 0; k4 < 32; k4++) {
                float4 w = W4[k4], u = U4[k4], zz = z4[k4], qq = q4[k4];
                aw += w.x * zz.x + w.y * zz.y + w.z * zz.z + w.w * zz.w;
                au += u.x * qq.x + u.y * qq.y + u.z * qq.z + u.w * qq.w;
            }
            float a = sigmoidf_(B[r * COLS + c] + aw + au);
            if (gate == 0) ul[r] = a;
            else rq[r] = a * qc[r];
        }
        __syncthreads();
        // phase 2: candidate gate + state update (tid < 128 only)
        if (tid < 128) {
            const float4* W4 = (const float4*)(Wh + r * 128);
            const float4* U4 = (const float4*)(Uh + r * 128);
            const float4* z4 = (const float4*)zc;
            const float4* rq4 = (const float4*)rq;
            float aw = 0.f, au = 0.f;
#pragma unroll 8
            for (int k4 = 0; k4 < 32; k4++) {
                float4 w = W4[k4], u = U4[k4], zz = z4[k4], qq = rq4[k4];
                aw += w.x * zz.x + w.y * zz.y + w.z * zz.z + w.w * zz.w;
                au += u.x * qq.x + u.y * qq.y + u.z * qq.z + u.w * qq.w;
            }
            float h = tanhf(Bh[r * COLS + c] + aw + au);
            float u = ul[r];
            float qn = (1.f - u) * qc[r] + u * h;
            Qn_all[(size_t)t * 128 * COLS + r * COLS + c] = qn;
            qc[r] = qn;    // own element; published at next loop-top barrier
        }
    }
}

// ---------------- XW(t) = X(t) @ Qn(t), 64-col slices for occupancy ----------------
// grid: (ceil(N/64), T_STEPS, ostride/64). Each block stages a 128x64 Q-slice (32KB LDS
// -> 5 blocks/CU vs 2 at 64KB) and computes 64 rows x 64 cols. Output values bitwise
// identical to the unsliced kernel (same k-order per element; columns partitioned).
template <bool BF16>
__global__ void __launch_bounds__(256)
xw_kernel(const float* __restrict__ X_b, const float* __restrict__ Qn_all,
          void* __restrict__ outp, int N, int ostride) {
    constexpr int SW = 64;          // slice width (cols)
    constexpr int TPR = SW / 4;     // 16 threads per row
    constexpr int RPG = 256 / TPR;  // 16 rows per group
    constexpr int RPB = RPG * 4;    // 64 rows per block
    int t = blockIdx.y;
    int coff = blockIdx.z * SW;
    const float* X = X_b + (size_t)t * N * FIN;
    const float* Qn = Qn_all + (size_t)t * 128 * ostride;
    __shared__ float4 qs[128 * TPR];   // 32 KB
    for (int i = threadIdx.x; i < 128 * TPR; i += 256) {
        int r = i / TPR, c4 = i % TPR;
        qs[i] = *(const float4*)(Qn + (size_t)r * ostride + coff + c4 * 4);
    }
    __syncthreads();
    int lane_c = threadIdx.x % TPR;
    int rloc = threadIdx.x / TPR;
    int base = blockIdx.x * RPB;
    int rows[4];
    float4 acc[4];
#pragma unroll
    for (int j = 0; j < 4; j++) {
        rows[j] = base + rloc + j * RPG;
        acc[j] = make_float4(0.f, 0.f, 0.f, 0.f);
    }
    int nc[4];
#pragma unroll
    for (int j = 0; j < 4; j++) nc[j] = min(rows[j], N - 1);

    for (int k4 = 0; k4 < 32; k4++) {
        float4 q0 = qs[(k4 * 4 + 0) * TPR + lane_c];
        float4 q1 = qs[(k4 * 4 + 1) * TPR + lane_c];
        float4 q2 = qs[(k4 * 4 + 2) * TPR + lane_c];
        float4 q3 = qs[(k4 * 4 + 3) * TPR + lane_c];
#pragma unroll
        for (int j = 0; j < 4; j++) {
            float4 xv = ((const float4*)(X + (size_t)nc[j] * FIN))[k4];
            acc[j].x += xv.x * q0.x + xv.y * q1.x + xv.z * q2.x + xv.w * q3.x;
            acc[j].y += xv.x * q0.y + xv.y * q1.y + xv.z * q2.y + xv.w * q3.y;
            acc[j].z += xv.x * q0.z + xv.y * q1.z + xv.z * q2.z + xv.w * q3.z;
            acc[j].w += xv.x * q0.w + xv.y * q1.w + xv.z * q2.w + xv.w * q3.w;
        }
    }
#pragma unroll
    for (int j = 0; j < 4; j++) {
        if (rows[j] < N) {
            if (BF16) {
                ushort4 o;
                o.x = f2bf(acc[j].x); o.y = f2bf(acc[j].y);
                o.z = f2bf(acc[j].z); o.w = f2bf(acc[j].w);
                ((ushort4*)((unsigned short*)outp + ((size_t)t * N + rows[j]) * ostride + coff))[lane_c] = o;
            } else {
                ((float4*)((float*)outp + ((size_t)t * N + rows[j]) * ostride + coff))[lane_c] = acc[j];
            }
        }
    }
}

// ---------------- batched CSR build over all 4 timesteps (sorted by (t,dst)) ----------------
__global__ void hist4_kernel(const int* __restrict__ dst, int* __restrict__ hist4, int E) {
    int e = blockIdx.x * blockDim.x + threadIdx.x;
    if (e >= E) return;
    int t = blockIdx.y;
    atomicAdd(&hist4[t * NNODES + dst[(size_t)t * E + e]], 1);
}

__global__ void __launch_bounds__(256)
scanA_kernel(const int* __restrict__ hist, int* __restrict__ incl, int* __restrict__ bsum, int M) {
    __shared__ int sh[256];
    int gid = blockIdx.x * 256 + threadIdx.x;
    int v = (gid < M) ? hist[gid] : 0;
    sh[threadIdx.x] = v;
    __syncthreads();
    for (int off = 1; off < 256; off <<= 1) {
        int u = (threadIdx.x >= off) ? sh[threadIdx.x - off] : 0;
        __syncthreads();
        sh[threadIdx.x] += u;
        __syncthreads();
    }
    if (gid < M) incl[gid] = sh[threadIdx.x];
    if (threadIdx.x == 255) bsum[blockIdx.x] = sh[255];
}

__global__ void __launch_bounds__(1024)
scanB_kernel(int* __restrict__ bsum, int nb) {
    __shared__ int sh[1024];
    int tid = threadIdx.x;
    int v = (tid < nb) ? bsum[tid] : 0;
    sh[tid] = v;
    __syncthreads();
    for (int off = 1; off < 1024; off <<= 1) {
        int u = (tid >= off) ? sh[tid - off] : 0;
        __syncthreads();
        sh[tid] += u;
        __syncthreads();
    }
    if (tid < nb) bsum[tid] = (tid == 0) ? 0 : sh[tid - 1];
}

__global__ void __launch_bounds__(256)
scanC_kernel(const int* __restrict__ hist, const int* __restrict__ incl,
             const int* __restrict__ bsum, int* __restrict__ row_ptr,
             int* __restrict__ cursor, int M) {
    int gid = blockIdx.x * 256 + threadIdx.x;
    if (gid < M) {
        int inc = incl[gid] + bsum[gid / 256];
        int ex = inc - hist[gid];
        row_ptr[gid] = ex;
        cursor[gid] = ex;
        if (gid == M - 1) row_ptr[M] = inc;
    }
}

// dst-range-sharded scatter (R7 win: keeps sedge writes XCD-local, lines coalesce)
__global__ void bucket4_kernel(const int* __restrict__ src, const int* __restrict__ dst,
                               const float* __restrict__ w, int* __restrict__ cursor,
                               int2* __restrict__ sedge, int E) {
    int bx = blockIdx.x;
    int shard = bx & 7;
    int e = (bx >> 3) * 256 + threadIdx.x;
    if (e >= E) return;
    int t = blockIdx.y;
    size_t ge = (size_t)t * E + e;
    int d = dst[ge];
    if (d / DSHARD != shard) return;
    int pos = atomicAdd(&cursor[t * NNODES + d], 1);
    int2 pk;
    pk.x = src[ge];
    pk.y = __float_as_int(w[ge]);
    sedge[pos] = pk;
}

// ---------------- L0 CSR aggregation, column-sliced: one launch per 32-col slice ----------------
// Each launch gathers exactly 1 cache line (128B) per edge from a 25.6MB chip-wide slice
// (6.4MB per t) -> L3-resident across the pass; launch boundary enforces phase alignment.
// Summation order per output element identical to the unsliced kernel (edge order unchanged).
// Scores accumulate across passes in scoreacc (one owner thread per (t,node) per pass).
template <int SW, bool SCORE>
__global__ void __launch_bounds__(256)
agg_slice_kernel(const float* __restrict__ XW_b, const int* __restrict__ row_ptr4,
                 const int2* __restrict__ sedge,
                 float* __restrict__ out_b, int N, int P,
                 const float* __restrict__ scorer, const float* __restrict__ norms,
                 const float* __restrict__ mask_b, float* __restrict__ scores_b,
                 int* __restrict__ ghist_b, float* __restrict__ scoreacc) {
    constexpr int TPN = SW / 4;        // 8 threads per node
    constexpr int NPB = 256 / TPN;     // 32 nodes per block
    constexpr int NPASS = FIN / SW;    // 4
    int lin = blockIdx.x;
    int xcd = lin & 7;
    int slot = lin >> 3;
    int t = xcd >> 1;                 // XCDs {0,1}->t0, {2,3}->t1, ...
    int db = slot * 2 + (xcd & 1);
    int dstBlocks = (N + NPB - 1) / NPB;
    if (db >= dstBlocks) return;
    int node = db * NPB + threadIdx.x / TPN;
    if (node >= N) return;
    int lane = threadIdx.x % TPN;
    const int* rp = row_ptr4 + (size_t)t * N;
    int beg = rp[node], end = rp[node + 1];
    const float* XW = XW_b + (size_t)t * N * FIN + P * SW;
    float4 a0 = make_float4(0.f, 0.f, 0.f, 0.f);
    float4 a1 = a0, a2 = a0, a3 = a0;
    int i = beg;
    for (; i + 4 <= end; i += 4) {
        int2 p0 = sedge[i], p1 = sedge[i + 1], p2 = sedge[i + 2], p3 = sedge[i + 3];
        float4 v0 = ((const float4*)(XW + (size_t)p0.x * FIN))[lane];
        float4 v1 = ((const float4*)(XW + (size_t)p1.x * FIN))[lane];
        float4 v2 = ((const float4*)(XW + (size_t)p2.x * FIN))[lane];
        float4 v3 = ((const float4*)(XW + (size_t)p3.x * FIN))[lane];
        float w0 = __int_as_float(p0.y), w1 = __int_as_float(p1.y);
        float w2 = __int_as_float(p2.y), w3 = __int_as_float(p3.y);
        a0.x += v0.x * w0; a0.y += v0.y * w0; a0.z += v0.z * w0; a0.w += v0.w * w0;
        a1.x += v1.x * w1; a1.y += v1.y * w1; a1.z += v1.z * w1; a1.w += v1.w * w1;
        a2.x += v2.x * w2; a2.y += v2.y * w2; a2.z += v2.z * w2; a2.w += v2.w * w2;
        a3.x += v3.x * w3; a3.y += v3.y * w3; a3.z += v3.z * w3; a3.w += v3.w * w3;
    }
    for (; i < end; i++) {
        int2 pk = sedge[i];
        float wt = __int_as_float(pk.y);
        float4 v = ((const float4*)(XW + (size_t)pk.x * FIN))[lane];
        a0.x += v.x * wt; a0.y += v.y * wt; a0.z += v.z * wt; a0.w += v.w * wt;
    }
    float4 acc;
    acc.x = (a0.x + a1.x) + (a2.x + a3.x);
    acc.y = (a0.y + a1.y) + (a2.y + a3.y);
    acc.z = (a0.z + a1.z) + (a2.z + a3.z);
    acc.w = (a0.w + a1.w) + (a2.w + a3.w);
    acc.x = fmaxf(acc.x, 0.f); acc.y = fmaxf(acc.y, 0.f);
    acc.z = fmaxf(acc.z, 0.f); acc.w = fmaxf(acc.w, 0.f);
    nt_store4(out_b + ((size_t)t * N + node) * FIN + P * SW + lane * 4, acc);
    if (SCORE) {
        float4 sc4 = ((const float4*)(scorer + P * SW))[lane];
        float partial = acc.x * sc4.x + acc.y * sc4.y + acc.z * sc4.z + acc.w * sc4.w;
#pragma unroll
        for (int off = TPN / 2; off > 0; off >>= 1) partial += __shfl_xor(partial, off, TPN);
        if (lane == 0) {
            float* sa = scoreacc + (size_t)t * N + node;
            float tot = (P == 0 ? 0.f : *sa) + partial;
            if (P == NPASS - 1) {
                float s = tot / norms[1] + mask_b[(size_t)t * N + node];
                scores_b[(size_t)t * N + node] = s;
                atomicAdd(&ghist_b[t * NBINS + (key_of(s) >> BINSHIFT)], 1);
            } else {
                *sa = tot;
            }
        }
    }
}

// ---------------- L1 CSR aggregation (bf16 gather, fp32 out) ----------------
// 1D grid; xcd = blockIdx&7 picks t (2 XCDs per t); per-t bf16 XW1 = 6.4MB.
template <int COLS>
__global__ void __launch_bounds__(256)
agg_kernel(const unsigned short* __restrict__ XWb, const int* __restrict__ row_ptr4,
           const int2* __restrict__ sedge,
           float* __restrict__ out_b, int N) {
    constexpr int TPN = COLS / 4;
    constexpr int NPB = 256 / TPN;
    int lin = blockIdx.x;
    int xcd = lin & 7;
    int slot = lin >> 3;
    int t = xcd >> 1;
    int db = slot * 2 + (xcd & 1);
    int dstBlocks = (N + NPB - 1) / NPB;
    if (db >= dstBlocks) return;
    int node = db * NPB + threadIdx.x / TPN;
    if (node >= N) return;
    int lane = threadIdx.x % TPN;
    const int* rp = row_ptr4 + (size_t)t * N;
    int beg = rp[node], end = rp[node + 1];
    const unsigned short* XW = XWb + (size_t)t * N * COLS;
    float4 a0 = make_float4(0.f, 0.f, 0.f, 0.f);
    float4 a1 = a0, a2 = a0, a3 = a0;
    int i = beg;
    for (; i + 4 <= end; i += 4) {
        int2 p0 = sedge[i], p1 = sedge[i + 1], p2 = sedge[i + 2], p3 = sedge[i + 3];
        ushort4 v0 = ((const ushort4*)(XW + (size_t)p0.x * COLS))[lane];
        ushort4 v1 = ((const ushort4*)(XW + (size_t)p1.x * COLS))[lane];
        ushort4 v2 = ((const ushort4*)(XW + (size_t)p2.x * COLS))[lane];
        ushort4 v3 = ((const ushort4*)(XW + (size_t)p3.x * COLS))[lane];
        float w0 = __int_as_float(p0.y), w1 = __int_as_float(p1.y);
        float w2 = __int_as_float(p2.y), w3 = __int_as_float(p3.y);
        a0.x += bf2f(v0.x) * w0; a0.y += bf2f(v0.y) * w0; a0.z += bf2f(v0.z) * w0; a0.w += bf2f(v0.w) * w0;
        a1.x += bf2f(v1.x) * w1; a1.y += bf2f(v1.y) * w1; a1.z += bf2f(v1.z) * w1; a1.w += bf2f(v1.w) * w1;
        a2.x += bf2f(v2.x) * w2; a2.y += bf2f(v2.y) * w2; a2.z += bf2f(v2.z) * w2; a2.w += bf2f(v2.w) * w2;
        a3.x += bf2f(v3.x) * w3; a3.y += bf2f(v3.y) * w3; a3.z += bf2f(v3.z) * w3; a3.w += bf2f(v3.w) * w3;
    }
    for (; i < end; i++) {
        int2 pk = sedge[i];
        float wt = __int_as_float(pk.y);
        ushort4 v = ((const ushort4*)(XW + (size_t)pk.x * COLS))[lane];
        a0.x += bf2f(v.x) * wt; a0.y += bf2f(v.y) * wt;
        a0.z += bf2f(v.z) * wt; a0.w += bf2f(v.w) * wt;
    }
    float4 acc;
    acc.x = (a0.x + a1.x) + (a2.x + a3.x);
    acc.y = (a0.y + a1.y) + (a2.y + a3.y);
    acc.z = (a0.z + a1.z) + (a2.z + a3.z);
    acc.w = (a0.w + a1.w) + (a2.w + a3.w);
    acc.x = fmaxf(acc.x, 0.f); acc.y = fmaxf(acc.y, 0.f);
    acc.z = fmaxf(acc.z, 0.f); acc.w = fmaxf(acc.w, 0.f);
    nt_store4(out_b + ((size_t)t * N + node) * COLS + lane * 4, acc);
}

extern "C" void kernel_launch(void* const* d_in, const int* in_sizes, int n_in,
                              void* d_out, int out_size, void* d_ws, size_t ws_size,
                              hipStream_t stream) {
    const float* node_embs   = (const float*)d_in[0];
    const float* mask        = (const float*)d_in[1];
    const int*   edge_src    = (const int*)d_in[2];
    const int*   edge_dst    = (const int*)d_in[3];
    const float* edge_weight = (const float*)d_in[4];
    const float* gcn_w0      = (const float*)d_in[5];
    const float* gcn_w1      = (const float*)d_in[6];
    const float* l0p[10];
    const float* l1p[10];
    for (int i = 0; i < 10; i++) l0p[i] = (const float*)d_in[7 + i];
    for (int i = 0; i < 10; i++) l1p[i] = (const float*)d_in[17 + i];
    // l*p: 0=Wu 1=Uu 2=Bu 3=Wr 4=Ur 5=Br 6=Wh 7=Uh 8=Bh 9=scorer

    char* ws = (char*)d_ws;
    size_t off = 0;
    auto alloc = [&](size_t bytes) -> void* {
        void* p = ws + off;
        off += (bytes + 255) / 256 * 256;
        return p;
    };
    float* XW0buf = (float*)alloc((size_t)4 * NNODES * 128 * 4);          // fp32, all t (102 MB)
    float* h1buf  = (float*)alloc((size_t)4 * NNODES * 128 * 4);          // fp32, all t (102 MB)
    unsigned short* XW1buf = (unsigned short*)alloc((size_t)4 * NNODES * 64 * 2);  // bf16, all t
    float* scores4= (float*)alloc((size_t)4 * NNODES * 4);                // L0 scores (all t)
    float* scores1= (float*)alloc((size_t)4 * NNODES * 4);                // L1 scores (all t)
    float* scoreacc=(float*)alloc((size_t)4 * NNODES * 4);                // partial L1 score dots
    float* z0buf  = (float*)alloc((size_t)4 * 128 * 128 * 4);
    float* z1buf  = (float*)alloc((size_t)4 * 128 * 64 * 4);
    float* Q0n    = (float*)alloc((size_t)4 * 128 * 128 * 4);
    float* Q1n    = (float*)alloc((size_t)4 * 128 * 64 * 4);
    float* norms  = (float*)alloc(64);
    // combined zeroed region: hist4[4N] + ghist0[4*NBINS] + ghist1[4*NBINS] + cnts[64]
    int* hist4    = (int*)alloc(((size_t)4 * NNODES + 8 * NBINS + 64) * 4);
    int* ghist0   = hist4 + 4 * NNODES;
    int* ghist1   = ghist0 + 4 * NBINS;
    int* cnts     = ghist1 + 4 * NBINS;
    int* incl4    = (int*)alloc((size_t)4 * NNODES * 4);
    int* bsumb    = (int*)alloc(1024 * 4);
    int* rowp4    = (int*)alloc(((size_t)4 * NNODES + 1) * 4);
    int* cursor4  = (int*)alloc((size_t)4 * NNODES * 4);
    int2* sedge4  = (int2*)alloc((size_t)4 * NEDGES * 8);
    int*   gt_idx = (int*)alloc((size_t)4 * 128 * 4);
    float* gt_val = (float*)alloc((size_t)4 * 128 * 4);
    int*   eq_idx = (int*)alloc((size_t)4 * EQCAP * 4);
    float* eq_val = (float*)alloc((size_t)4 * EQCAP * 4);

    hipMemsetAsync(hist4, 0, ((size_t)4 * NNODES + 8 * NBINS + 64) * 4, stream);
    norm_kernel<<<1, 128, 0, stream>>>(l0p[9], l1p[9], norms);

    const int M4 = 4 * NNODES;
    const int NB4 = (M4 + 255) / 256;          // 782
    const int NB = (NNODES + 255) / 256;       // 196
    const int EB = (NEDGES + 255) / 256;       // 1563

    // ---- batched CSR build for all 4 timesteps ----
    hist4_kernel<<<dim3(EB, 4), 256, 0, stream>>>(edge_dst, hist4, NEDGES);
    scanA_kernel<<<NB4, 256, 0, stream>>>(hist4, incl4, bsumb, M4);
    scanB_kernel<<<1, 1024, 0, stream>>>(bsumb, NB4);
    scanC_kernel<<<NB4, 256, 0, stream>>>(hist4, incl4, bsumb, rowp4, cursor4, M4);
    bucket4_kernel<<<dim3(EB * 8, 4), 256, 0, stream>>>(edge_src, edge_dst, edge_weight, cursor4, sedge4, NEDGES);

    // ---- L0: scores + top-k + z for ALL t (input-only dependence) ----
    scores_hist4_kernel<<<dim3(NB, 4), 256, 0, stream>>>(node_embs, l0p[9], norms, mask, scores4, ghist0, NNODES);
    topk_collect_kernel<<<dim3(NB, 4), 256, 0, stream>>>(scores4, ghist0, cnts, gt_idx, gt_val, eq_idx, eq_val, NNODES, 128);
    topk_finish_kernel<128><<<4, 1024, 0, stream>>>(ghist0, cnts, gt_idx, gt_val, eq_idx, eq_val, node_embs, z0buf, NNODES);

    // ---- L0 GRU recurrence (all t, one kernel), then batched XW + sliced agg ----
    gru_multi_kernel<128><<<128, 256, 0, stream>>>(gcn_w0, z0buf,
        l0p[0], l0p[1], l0p[2], l0p[3], l0p[4], l0p[5], l0p[6], l0p[7], l0p[8], Q0n);
    {
        const int RB = (NNODES + 63) / 64;                  // 782
        xw_kernel<false><<<dim3(RB, 4, 2), 256, 0, stream>>>(node_embs, Q0n, XW0buf, NNODES, 128);
    }
    {
        const int dstBlocksS = (NNODES + 31) / 32;          // 1563 (NPB=32 for SW=32)
        const int gridS = ((dstBlocksS + 1) / 2) * 8;       // 6256
        for (int P = 0; P < 4; P++) {
            agg_slice_kernel<32, true><<<gridS, 256, 0, stream>>>(XW0buf, rowp4, sedge4, h1buf, NNODES, P,
                l1p[9], norms, mask, scores1, ghist1, scoreacc);
        }
    }

    // ---- L1: top-k for all t (h1+scores1 ready), GRU recurrence, batched XW + agg -> d_out ----
    topk_collect_kernel<<<dim3(NB, 4), 256, 0, stream>>>(scores1, ghist1, cnts, gt_idx, gt_val, eq_idx, eq_val, NNODES, 64);
    topk_finish_kernel<64><<<4, 1024, 0, stream>>>(ghist1, cnts, gt_idx, gt_val, eq_idx, eq_val, h1buf, z1buf, NNODES);
    gru_multi_kernel<64><<<64, 256, 0, stream>>>(gcn_w1, z1buf,
        l1p[0], l1p[1], l1p[2], l1p[3], l1p[4], l1p[5], l1p[6], l1p[7], l1p[8], Q1n);
    {
        const int RB = (NNODES + 63) / 64;                  // 782
        xw_kernel<true><<<dim3(RB, 4, 1), 256, 0, stream>>>(h1buf, Q1n, XW1buf, NNODES, 64);
    }
    {
        const int dstBlocks1 = (NNODES + 15) / 16;          // 3125 (NPB=16 for COLS=64)
        const int grid1 = ((dstBlocks1 + 1) / 2) * 8;       // 12504
        agg_kernel<64><<<grid1, 256, 0, stream>>>(XW1buf, rowp4, sedge4, (float*)d_out, NNODES);
    }
}